// Round 13
// baseline (583.529 us; speedup 1.0000x reference)
//
#include <hip/hip_runtime.h>
#include <hip/hip_bf16.h>

#define NN 100000
#define EE 1000000
#define GG 128
#define NT 782               // node tiles of 128 (782*128 = 100096)
#define BN_EPS 1e-5f

// workspace float offsets
#define X0_OFF    0L          // x ping: packed bf16 [100096][64]
#define X1_OFF    3250000L    // x pong
#define WT1_OFF   12806144L   // fh layer1 scaled cols [128][64]
#define C1_OFF    12814336L
#define WT2_OFF   12814400L   // fh layer2 scaled cols [64][64]
#define C2_OFF    12818496L
#define WTC1_OFF  12818560L   // conv layer1 x3
#define CC1_OFF   12830848L
#define WTC2_OFF  12831040L   // conv layer2 x3
#define CC2_OFF   12843328L
#define POOL_OFF  12843520L   // 4 stages * 128 * 64
#define CNT_OFF   12876288L   // 128
// int-typed views
#define COL_OFF   12876416L   // 1,000,000
#define CUR_OFF   13876416L   // 100,000
#define BSUM_OFF  13976416L   // 128

#define SCAN_BLK 1024
#define SCAN_NBLK ((NN + SCAN_BLK - 1) / SCAN_BLK)   // 98
#define COLS_CAP 2048

__device__ __forceinline__ float bf_lo(unsigned v) { return __uint_as_float(v << 16); }
__device__ __forceinline__ float bf_hi(unsigned v) { return __uint_as_float(v & 0xffff0000u); }
__device__ __forceinline__ unsigned f2bf(float f) {
    unsigned b = __float_as_uint(f);
    return (b + 0x7fffu + ((b >> 16) & 1u)) >> 16;   // RNE
}

// ---------------- prep: fold BN scale into weight columns ----------------
__global__ void prep_kernel(
    const float* __restrict__ fh_W1, const float* __restrict__ fh_b1, const float* __restrict__ fh_g1,
    const float* __restrict__ fh_bt1, const float* __restrict__ fh_m1, const float* __restrict__ fh_v1,
    const float* __restrict__ fh_W2, const float* __restrict__ fh_b2, const float* __restrict__ fh_g2,
    const float* __restrict__ fh_bt2, const float* __restrict__ fh_m2, const float* __restrict__ fh_v2,
    const float* __restrict__ cW1, const float* __restrict__ cb1, const float* __restrict__ cg1,
    const float* __restrict__ cbt1, const float* __restrict__ cm1, const float* __restrict__ cv1,
    const float* __restrict__ cW2, const float* __restrict__ cb2, const float* __restrict__ cg2,
    const float* __restrict__ cbt2, const float* __restrict__ cm2, const float* __restrict__ cv2,
    float* __restrict__ ws)
{
    int job = blockIdx.x;
    const float *W, *b, *g, *bt, *m, *v;
    float *Wo, *Co;
    int K;
    if (job == 0) {
        W = fh_W1; b = fh_b1; g = fh_g1; bt = fh_bt1; m = fh_m1; v = fh_v1;
        Wo = ws + WT1_OFF; Co = ws + C1_OFF; K = 128;
    } else if (job == 1) {
        W = fh_W2; b = fh_b2; g = fh_g2; bt = fh_bt2; m = fh_m2; v = fh_v2;
        Wo = ws + WT2_OFF; Co = ws + C2_OFF; K = 64;
    } else if (job <= 4) {
        int l = job - 2;
        W = cW1 + l * 4096; b = cb1 + l * 64; g = cg1 + l * 64; bt = cbt1 + l * 64;
        m = cm1 + l * 64; v = cv1 + l * 64;
        Wo = ws + WTC1_OFF + l * 4096; Co = ws + CC1_OFF + l * 64; K = 64;
    } else {
        int l = job - 5;
        W = cW2 + l * 4096; b = cb2 + l * 64; g = cg2 + l * 64; bt = cbt2 + l * 64;
        m = cm2 + l * 64; v = cv2 + l * 64;
        Wo = ws + WTC2_OFF + l * 4096; Co = ws + CC2_OFF + l * 64; K = 64;
    }
    int tot = 64 * K;
    for (int i = threadIdx.x; i < tot; i += blockDim.x) {
        int j = i & 63;
        float s = g[j] * rsqrtf(v[j] + BN_EPS);
        Wo[i] = W[i] * s;   // [k][j] layout, scale column j
    }
    if (threadIdx.x < 64) {
        int j = threadIdx.x;
        float s = g[j] * rsqrtf(v[j] + BN_EPS);
        Co[j] = (b[j] - m[j]) * s + bt[j];
    }
}

// ---------------- CSR build ----------------
__global__ __launch_bounds__(256) void hist_kernel(const int* __restrict__ edges, int* __restrict__ cnt)
{
    int e = blockIdx.x * blockDim.x + threadIdx.x;
    if (e >= EE) return;
    atomicAdd(&cnt[edges[EE + e]], 1);
}

__global__ __launch_bounds__(SCAN_BLK) void scan_pass1(const int* __restrict__ cnt, int* __restrict__ bsum)
{
    __shared__ int r[SCAN_BLK];
    int t = threadIdx.x;
    int i = blockIdx.x * SCAN_BLK + t;
    r[t] = (i < NN) ? cnt[i] : 0;
    __syncthreads();
    for (int off = SCAN_BLK / 2; off > 0; off >>= 1) {
        if (t < off) r[t] += r[t + off];
        __syncthreads();
    }
    if (t == 0) bsum[blockIdx.x] = r[0];
}

__global__ __launch_bounds__(128) void scan_pass2(int* __restrict__ bsum)
{
    __shared__ int s[128];
    int t = threadIdx.x;
    int v = (t < SCAN_NBLK) ? bsum[t] : 0;
    s[t] = v;
    __syncthreads();
    for (int off = 1; off < 128; off <<= 1) {
        int a = (t >= off) ? s[t - off] : 0;
        __syncthreads();
        s[t] += a;
        __syncthreads();
    }
    if (t < SCAN_NBLK) bsum[t] = s[t] - v;   // exclusive
}

__global__ __launch_bounds__(SCAN_BLK) void scan_pass3(int* __restrict__ cnt, const int* __restrict__ bsum)
{
    __shared__ int s[SCAN_BLK];
    int t = threadIdx.x;
    int i = blockIdx.x * SCAN_BLK + t;
    int v = (i < NN) ? cnt[i] : 0;
    s[t] = v;
    __syncthreads();
    for (int off = 1; off < SCAN_BLK; off <<= 1) {
        int a = (t >= off) ? s[t - off] : 0;
        __syncthreads();
        s[t] += a;
        __syncthreads();
    }
    if (i < NN) cnt[i] = bsum[blockIdx.x] + s[t] - v;   // exclusive start
}

__global__ __launch_bounds__(256) void fill_kernel(
    const int* __restrict__ edges, int* __restrict__ cursor, int* __restrict__ col)
{
    int e = blockIdx.x * blockDim.x + threadIdx.x;
    if (e >= EE) return;
    int dst = edges[EE + e];
    int p = atomicAdd(&cursor[dst], 1);
    col[p] = edges[e];
}
// after fill: cursor[n] == row end; start = (n==0)?0:cursor[n-1]

// ---------------- fused gather + conv MLP + pool (cursor-prefetch, col in LDS) ----------------
__global__ __launch_bounds__(256) void gconv_fused_kernel(
    const unsigned* __restrict__ xin, const int* __restrict__ cursor, const int* __restrict__ col,
    const float* __restrict__ W1s, const float* __restrict__ C1v,
    const float* __restrict__ W2s, const float* __restrict__ C2v,
    const int* __restrict__ batch,
    unsigned* __restrict__ xout, float* __restrict__ pooled)
{
    __shared__ float ldsB[64 * 65];   // gather acc [feat][node] -> later H
    __shared__ int colS[COLS_CAP];
    int t = threadIdx.x;
    int lane = t & 63;
    int wv = t >> 6;
    int nbase = blockIdx.x << 6;

    // cursor prefetch: lane L holds start/end of node nbase+L (2 coalesced loads)
    int nL = nbase + lane;
    int myStart = 0, myEnd = 0;
    if (nL < NN) {
        myStart = (nL == 0) ? 0 : cursor[nL - 1];
        myEnd = cursor[nL];
    }
    int lastN = NN - 1 - nbase;
    if (lastN > 63) lastN = 63;
    if (lastN < 0) lastN = 0;
    int bs = __shfl(myStart, 0);
    int be = __shfl(myEnd, lastN);
    int ecount = be - bs;
    bool inLds = (ecount <= COLS_CAP);
    if (inLds) {
        for (int i = t; i < ecount; i += 256) colS[i] = col[bs + i];
    }
    __syncthreads();

    // ---- gather phase (register accumulation) ----
    {
        int q = lane >> 3, c = lane & 7;
        const uint4* x4 = (const uint4*)xin;
        for (int s = 0; s < 16; s++) {
            int i = (wv << 4) + s;
            int n = nbase + i;
            if (n < NN) {
                int st = __shfl(myStart, i);
                int en = __shfl(myEnd, i);
                float acc[8];
                if (q == 0) {
                    uint4 u = x4[(long)n * 8 + c];
                    acc[0] = bf_lo(u.x); acc[1] = bf_hi(u.x);
                    acc[2] = bf_lo(u.y); acc[3] = bf_hi(u.y);
                    acc[4] = bf_lo(u.z); acc[5] = bf_hi(u.z);
                    acc[6] = bf_lo(u.w); acc[7] = bf_hi(u.w);
                } else {
#pragma unroll
                    for (int r = 0; r < 8; r++) acc[r] = 0.f;
                }
                if (inLds) {
                    for (int b2 = st + q; b2 < en; b2 += 8) {
                        int sc = colS[b2 - bs];
                        uint4 u = x4[(long)sc * 8 + c];
                        acc[0] += bf_lo(u.x); acc[1] += bf_hi(u.x);
                        acc[2] += bf_lo(u.y); acc[3] += bf_hi(u.y);
                        acc[4] += bf_lo(u.z); acc[5] += bf_hi(u.z);
                        acc[6] += bf_lo(u.w); acc[7] += bf_hi(u.w);
                    }
                } else {
                    for (int b2 = st + q; b2 < en; b2 += 8) {
                        int sc = col[b2];
                        uint4 u = x4[(long)sc * 8 + c];
                        acc[0] += bf_lo(u.x); acc[1] += bf_hi(u.x);
                        acc[2] += bf_lo(u.y); acc[3] += bf_hi(u.y);
                        acc[4] += bf_lo(u.z); acc[5] += bf_hi(u.z);
                        acc[6] += bf_lo(u.w); acc[7] += bf_hi(u.w);
                    }
                }
#pragma unroll
                for (int d = 8; d <= 32; d <<= 1) {
#pragma unroll
                    for (int r = 0; r < 8; r++) acc[r] += __shfl_xor(acc[r], d);
                }
                if (q == 0) {
                    int f = c << 3;
#pragma unroll
                    for (int r = 0; r < 8; r++) ldsB[(f + r) * 65 + i] = acc[r];
                }
            }
        }
    }
    __syncthreads();

    // ---- MLP layer 1 ----
    int wvu = __builtin_amdgcn_readfirstlane(wv);
    float a[16];
#pragma unroll
    for (int j = 0; j < 16; j++) a[j] = C1v[wvu * 16 + j];
#pragma unroll 4
    for (int k = 0; k < 64; k++) {
        float xk = ldsB[k * 65 + lane];
        const float* w = W1s + k * 64 + wvu * 16;
#pragma unroll
        for (int j = 0; j < 16; j++) a[j] += xk * w[j];
    }
    __syncthreads();   // all X reads done; safe to overwrite with H
#pragma unroll
    for (int j = 0; j < 16; j++) ldsB[(wvu * 16 + j) * 65 + lane] = fmaxf(a[j], 0.f);
    __syncthreads();

    // ---- MLP layer 2 ----
    float o[16];
#pragma unroll
    for (int j = 0; j < 16; j++) o[j] = C2v[wvu * 16 + j];
#pragma unroll 4
    for (int k = 0; k < 64; k++) {
        float hk = ldsB[k * 65 + lane];
        const float* w = W2s + k * 64 + wvu * 16;
#pragma unroll
        for (int j = 0; j < 16; j++) o[j] += hk * w[j];
    }
#pragma unroll
    for (int j = 0; j < 16; j++) o[j] = fmaxf(o[j], 0.f);

    int n = nbase + lane;
    if (n < NN) {
        unsigned u[8];
#pragma unroll
        for (int p = 0; p < 8; p++) u[p] = f2bf(o[2 * p]) | (f2bf(o[2 * p + 1]) << 16);
        uint4* xo = (uint4*)(xout + ((long)n << 5) + (wvu << 3));
        xo[0] = make_uint4(u[0], u[1], u[2], u[3]);
        xo[1] = make_uint4(u[4], u[5], u[6], u[7]);
    }

    // ---- fused pool: ballot-segmented reduction over sorted batch ----
    int bg = (n < NN) ? batch[n] : -1;
    int bprev = __shfl(bg, (lane == 0) ? 0 : lane - 1);
    bool bound = (lane == 0) || (bg != bprev);
    unsigned long long m = __ballot(bound);
    int p = 0;
    while (p < 64) {
        unsigned long long rest = (p < 63) ? (m & (~0ULL << (p + 1))) : 0ULL;
        int np = rest ? (__ffsll((long long)rest) - 1) : 64;
        int g = __shfl(bg, p);
        if (g >= 0) {
            bool in = (lane >= p) && (lane < np);
#pragma unroll
            for (int j = 0; j < 16; j++) {
                float v = in ? o[j] : 0.f;
                v += __shfl_xor(v, 1);  v += __shfl_xor(v, 2);
                v += __shfl_xor(v, 4);  v += __shfl_xor(v, 8);
                v += __shfl_xor(v, 16); v += __shfl_xor(v, 32);
                if (lane == p) unsafeAtomicAdd(&pooled[g * 64 + wvu * 16 + j], v);
            }
        }
        p = np;
    }
}

// ---------------- fused first MLP: embedding -> x (bf16) + stage-0 pool/cnt ----------------
__global__ __launch_bounds__(256) void embed_fused_kernel(
    const int* __restrict__ node_ids, const float* __restrict__ emb,
    const float* __restrict__ W1s, const float* __restrict__ C1v,
    const float* __restrict__ W2s, const float* __restrict__ C2v,
    const int* __restrict__ batch,
    unsigned* __restrict__ xb, float* __restrict__ pooled, float* __restrict__ cnt)
{
    __shared__ float ldsB[64 * 129];   // E rows [node][k]; later H [feat][node]
    __shared__ int sh_nid[64];
    int t = threadIdx.x;
    int lane = t & 63;
    int wvu = __builtin_amdgcn_readfirstlane(t >> 6);
    int nbase = blockIdx.x << 6;
    if (t < 64) {
        int n0 = nbase + t;
        sh_nid[t] = (n0 < NN) ? node_ids[n0] : 0;
    }
    __syncthreads();
    for (int idx = t; idx < 8192; idx += 256) {
        int r = idx >> 7, c = idx & 127;
        ldsB[r * 129 + c] = emb[(long)sh_nid[r] * 128 + c];
    }
    __syncthreads();
    float a[16];
#pragma unroll
    for (int j = 0; j < 16; j++) a[j] = C1v[wvu * 16 + j];
#pragma unroll 4
    for (int k = 0; k < 128; k++) {
        float ek = ldsB[lane * 129 + k];
        const float* w = W1s + k * 64 + wvu * 16;
#pragma unroll
        for (int j = 0; j < 16; j++) a[j] += ek * w[j];
    }
    __syncthreads();   // E reads done; reuse buffer for H
#pragma unroll
    for (int j = 0; j < 16; j++) ldsB[(wvu * 16 + j) * 65 + lane] = fmaxf(a[j], 0.f);
    __syncthreads();
    float o[16];
#pragma unroll
    for (int j = 0; j < 16; j++) o[j] = C2v[wvu * 16 + j];
#pragma unroll 4
    for (int k = 0; k < 64; k++) {
        float hk = ldsB[k * 65 + lane];
        const float* w = W2s + k * 64 + wvu * 16;
#pragma unroll
        for (int j = 0; j < 16; j++) o[j] += hk * w[j];
    }
#pragma unroll
    for (int j = 0; j < 16; j++) o[j] = fmaxf(o[j], 0.f);

    int n = nbase + lane;
    if (n < NN) {
        unsigned u[8];
#pragma unroll
        for (int p = 0; p < 8; p++) u[p] = f2bf(o[2 * p]) | (f2bf(o[2 * p + 1]) << 16);
        uint4* xo = (uint4*)(xb + ((long)n << 5) + (wvu << 3));
        xo[0] = make_uint4(u[0], u[1], u[2], u[3]);
        xo[1] = make_uint4(u[4], u[5], u[6], u[7]);
    }

    int bg = (n < NN) ? batch[n] : -1;
    int bprev = __shfl(bg, (lane == 0) ? 0 : lane - 1);
    bool bound = (lane == 0) || (bg != bprev);
    unsigned long long m = __ballot(bound);
    int p = 0;
    while (p < 64) {
        unsigned long long rest = (p < 63) ? (m & (~0ULL << (p + 1))) : 0ULL;
        int np = rest ? (__ffsll((long long)rest) - 1) : 64;
        int g = __shfl(bg, p);
        if (g >= 0) {
            bool in = (lane >= p) && (lane < np);
#pragma unroll
            for (int j = 0; j < 16; j++) {
                float v = in ? o[j] : 0.f;
                v += __shfl_xor(v, 1);  v += __shfl_xor(v, 2);
                v += __shfl_xor(v, 4);  v += __shfl_xor(v, 8);
                v += __shfl_xor(v, 16); v += __shfl_xor(v, 32);
                if (lane == p) unsafeAtomicAdd(&pooled[g * 64 + wvu * 16 + j], v);
            }
            if (wvu == 0 && lane == p) unsafeAtomicAdd(&cnt[g], (float)(np - p));
        }
        p = np;
    }
}

// ---------------- readout + softmax ----------------
__global__ void final_kernel(
    const float* __restrict__ pooled, const float* __restrict__ cnt,
    const float* __restrict__ linW, const float* __restrict__ linb,
    float* __restrict__ outp)
{
    int g = threadIdx.x;
    if (g >= GG) return;
    float z0 = 0.f, z1 = 0.f;
    float c = cnt[g];
    for (int l = 0; l < 4; l++) {
        const float* p = pooled + (long)l * GG * 64 + (long)g * 64;
        const float* W = linW + l * 128;
        float bscale = (l == 0) ? c : 1.f;   // layer0 bias summed per node; others once
        float s0 = linb[l * 2 + 0] * bscale;
        float s1 = linb[l * 2 + 1] * bscale;
        for (int k = 0; k < 64; k++) {
            float pk = p[k];
            s0 += pk * W[k * 2 + 0];
            s1 += pk * W[k * 2 + 1];
        }
        z0 += s0; z1 += s1;
    }
    float mx = fmaxf(z0, z1);
    float e0 = expf(z0 - mx), e1 = expf(z1 - mx);
    float inv = 1.f / (e0 + e1);
    outp[g * 2 + 0] = e0 * inv;
    outp[g * 2 + 1] = e1 * inv;
}

extern "C" void kernel_launch(void* const* d_in, const int* in_sizes, int n_in,
                              void* d_out, int out_size, void* d_ws, size_t ws_size,
                              hipStream_t stream) {
    const int*   node_ids = (const int*)d_in[0];
    const int*   edges    = (const int*)d_in[1];
    const int*   batch    = (const int*)d_in[2];
    const float* emb      = (const float*)d_in[3];
    const float* fh_W1 = (const float*)d_in[4];
    const float* fh_b1 = (const float*)d_in[5];
    const float* fh_g1 = (const float*)d_in[6];
    const float* fh_bt1 = (const float*)d_in[7];
    const float* fh_m1 = (const float*)d_in[8];
    const float* fh_v1 = (const float*)d_in[9];
    const float* fh_W2 = (const float*)d_in[10];
    const float* fh_b2 = (const float*)d_in[11];
    const float* fh_g2 = (const float*)d_in[12];
    const float* fh_bt2 = (const float*)d_in[13];
    const float* fh_m2 = (const float*)d_in[14];
    const float* fh_v2 = (const float*)d_in[15];
    const float* cW1 = (const float*)d_in[16];
    const float* cb1 = (const float*)d_in[17];
    const float* cg1 = (const float*)d_in[18];
    const float* cbt1 = (const float*)d_in[19];
    const float* cm1 = (const float*)d_in[20];
    const float* cv1 = (const float*)d_in[21];
    const float* cW2 = (const float*)d_in[22];
    const float* cb2 = (const float*)d_in[23];
    const float* cg2 = (const float*)d_in[24];
    const float* cbt2 = (const float*)d_in[25];
    const float* cm2 = (const float*)d_in[26];
    const float* cv2 = (const float*)d_in[27];
    const float* linW = (const float*)d_in[28];
    const float* linb = (const float*)d_in[29];

    float*    ws     = (float*)d_ws;
    int*      cursor = (int*)(ws + CUR_OFF);
    int*      col    = (int*)(ws + COL_OFF);
    int*      bsum   = (int*)(ws + BSUM_OFF);
    unsigned* x0     = (unsigned*)(ws + X0_OFF);
    unsigned* x1     = (unsigned*)(ws + X1_OFF);

    prep_kernel<<<8, 256, 0, stream>>>(
        fh_W1, fh_b1, fh_g1, fh_bt1, fh_m1, fh_v1,
        fh_W2, fh_b2, fh_g2, fh_bt2, fh_m2, fh_v2,
        cW1, cb1, cg1, cbt1, cm1, cv1,
        cW2, cb2, cg2, cbt2, cm2, cv2, ws);

    hipMemsetAsync(ws + POOL_OFF, 0, (4L * GG * 64 + GG) * sizeof(float), stream);
    hipMemsetAsync(cursor, 0, NN * sizeof(int), stream);

    // CSR build (dst-indexed, single-pass fill)
    hist_kernel<<<(EE + 255) / 256, 256, 0, stream>>>(edges, cursor);
    scan_pass1<<<SCAN_NBLK, SCAN_BLK, 0, stream>>>(cursor, bsum);
    scan_pass2<<<1, 128, 0, stream>>>(bsum);
    scan_pass3<<<SCAN_NBLK, SCAN_BLK, 0, stream>>>(cursor, bsum);
    fill_kernel<<<(EE + 255) / 256, 256, 0, stream>>>(edges, cursor, col);

    const int FBLK = NT * 2;   // 1564 blocks (64 nodes each)

    embed_fused_kernel<<<FBLK, 256, 0, stream>>>(
        node_ids, emb, ws + WT1_OFF, ws + C1_OFF, ws + WT2_OFF, ws + C2_OFF,
        batch, x0, ws + POOL_OFF, ws + CNT_OFF);

    unsigned* xin = x0;
    unsigned* xout = x1;
    for (int l = 0; l < 3; l++) {
        gconv_fused_kernel<<<FBLK, 256, 0, stream>>>(
            xin, cursor, col,
            ws + WTC1_OFF + l * 4096, ws + CC1_OFF + l * 64,
            ws + WTC2_OFF + l * 4096, ws + CC2_OFF + l * 64,
            batch, xout, ws + POOL_OFF + (long)(l + 1) * GG * 64);
        unsigned* tmp = xin; xin = xout; xout = tmp;
    }

    final_kernel<<<1, 128, 0, stream>>>(
        ws + POOL_OFF, ws + CNT_OFF, linW, linb, (float*)d_out);
}

// Round 14
// 533.804 us; speedup vs baseline: 1.0932x; 1.0932x over previous
//
#include <hip/hip_runtime.h>
#include <hip/hip_bf16.h>

#define NN 100000
#define EE 1000000
#define GG 128
#define NT 782               // node tiles of 128 (782*128 = 100096)
#define BN_EPS 1e-5f

// workspace float offsets
#define X0_OFF    0L          // x ping: packed bf16 [100096][64]
#define X1_OFF    3250000L    // x pong
#define WT1_OFF   12806144L   // fh layer1 scaled cols [128][64]
#define C1_OFF    12814336L
#define WT2_OFF   12814400L   // fh layer2 scaled cols [64][64]
#define C2_OFF    12818496L
#define WTC1_OFF  12818560L   // conv layer1 x3
#define CC1_OFF   12830848L
#define WTC2_OFF  12831040L   // conv layer2 x3
#define CC2_OFF   12843328L
#define POOL_OFF  12843520L   // 4 stages * 128 * 64
#define CNT_OFF   12876288L   // 128
// int-typed views
#define COL_OFF   12876416L   // 1,000,000
#define CUR_OFF   13876416L   // 100,000
#define BSUM_OFF  13976416L   // 128

#define SCAN_BLK 1024
#define SCAN_NBLK ((NN + SCAN_BLK - 1) / SCAN_BLK)   // 98

__device__ __forceinline__ float bf_lo(unsigned v) { return __uint_as_float(v << 16); }
__device__ __forceinline__ float bf_hi(unsigned v) { return __uint_as_float(v & 0xffff0000u); }
__device__ __forceinline__ unsigned f2bf(float f) {
    unsigned b = __float_as_uint(f);
    return (b + 0x7fffu + ((b >> 16) & 1u)) >> 16;   // RNE
}

// ---------------- prep: fold BN scale into weight columns ----------------
__global__ void prep_kernel(
    const float* __restrict__ fh_W1, const float* __restrict__ fh_b1, const float* __restrict__ fh_g1,
    const float* __restrict__ fh_bt1, const float* __restrict__ fh_m1, const float* __restrict__ fh_v1,
    const float* __restrict__ fh_W2, const float* __restrict__ fh_b2, const float* __restrict__ fh_g2,
    const float* __restrict__ fh_bt2, const float* __restrict__ fh_m2, const float* __restrict__ fh_v2,
    const float* __restrict__ cW1, const float* __restrict__ cb1, const float* __restrict__ cg1,
    const float* __restrict__ cbt1, const float* __restrict__ cm1, const float* __restrict__ cv1,
    const float* __restrict__ cW2, const float* __restrict__ cb2, const float* __restrict__ cg2,
    const float* __restrict__ cbt2, const float* __restrict__ cm2, const float* __restrict__ cv2,
    float* __restrict__ ws)
{
    int job = blockIdx.x;
    const float *W, *b, *g, *bt, *m, *v;
    float *Wo, *Co;
    int K;
    if (job == 0) {
        W = fh_W1; b = fh_b1; g = fh_g1; bt = fh_bt1; m = fh_m1; v = fh_v1;
        Wo = ws + WT1_OFF; Co = ws + C1_OFF; K = 128;
    } else if (job == 1) {
        W = fh_W2; b = fh_b2; g = fh_g2; bt = fh_bt2; m = fh_m2; v = fh_v2;
        Wo = ws + WT2_OFF; Co = ws + C2_OFF; K = 64;
    } else if (job <= 4) {
        int l = job - 2;
        W = cW1 + l * 4096; b = cb1 + l * 64; g = cg1 + l * 64; bt = cbt1 + l * 64;
        m = cm1 + l * 64; v = cv1 + l * 64;
        Wo = ws + WTC1_OFF + l * 4096; Co = ws + CC1_OFF + l * 64; K = 64;
    } else {
        int l = job - 5;
        W = cW2 + l * 4096; b = cb2 + l * 64; g = cg2 + l * 64; bt = cbt2 + l * 64;
        m = cm2 + l * 64; v = cv2 + l * 64;
        Wo = ws + WTC2_OFF + l * 4096; Co = ws + CC2_OFF + l * 64; K = 64;
    }
    int tot = 64 * K;
    for (int i = threadIdx.x; i < tot; i += blockDim.x) {
        int j = i & 63;
        float s = g[j] * rsqrtf(v[j] + BN_EPS);
        Wo[i] = W[i] * s;   // [k][j] layout, scale column j
    }
    if (threadIdx.x < 64) {
        int j = threadIdx.x;
        float s = g[j] * rsqrtf(v[j] + BN_EPS);
        Co[j] = (b[j] - m[j]) * s + bt[j];
    }
}

// ---------------- CSR build ----------------
__global__ __launch_bounds__(256) void hist_kernel(const int* __restrict__ edges, int* __restrict__ cnt)
{
    int e = blockIdx.x * blockDim.x + threadIdx.x;
    if (e >= EE) return;
    atomicAdd(&cnt[edges[EE + e]], 1);
}

__global__ __launch_bounds__(SCAN_BLK) void scan_pass1(const int* __restrict__ cnt, int* __restrict__ bsum)
{
    __shared__ int r[SCAN_BLK];
    int t = threadIdx.x;
    int i = blockIdx.x * SCAN_BLK + t;
    r[t] = (i < NN) ? cnt[i] : 0;
    __syncthreads();
    for (int off = SCAN_BLK / 2; off > 0; off >>= 1) {
        if (t < off) r[t] += r[t + off];
        __syncthreads();
    }
    if (t == 0) bsum[blockIdx.x] = r[0];
}

__global__ __launch_bounds__(128) void scan_pass2(int* __restrict__ bsum)
{
    __shared__ int s[128];
    int t = threadIdx.x;
    int v = (t < SCAN_NBLK) ? bsum[t] : 0;
    s[t] = v;
    __syncthreads();
    for (int off = 1; off < 128; off <<= 1) {
        int a = (t >= off) ? s[t - off] : 0;
        __syncthreads();
        s[t] += a;
        __syncthreads();
    }
    if (t < SCAN_NBLK) bsum[t] = s[t] - v;   // exclusive
}

__global__ __launch_bounds__(SCAN_BLK) void scan_pass3(int* __restrict__ cnt, const int* __restrict__ bsum)
{
    __shared__ int s[SCAN_BLK];
    int t = threadIdx.x;
    int i = blockIdx.x * SCAN_BLK + t;
    int v = (i < NN) ? cnt[i] : 0;
    s[t] = v;
    __syncthreads();
    for (int off = 1; off < SCAN_BLK; off <<= 1) {
        int a = (t >= off) ? s[t - off] : 0;
        __syncthreads();
        s[t] += a;
        __syncthreads();
    }
    if (i < NN) cnt[i] = bsum[blockIdx.x] + s[t] - v;   // exclusive start
}

__global__ __launch_bounds__(256) void fill_kernel(
    const int* __restrict__ edges, int* __restrict__ cursor, int* __restrict__ col)
{
    int e = blockIdx.x * blockDim.x + threadIdx.x;
    if (e >= EE) return;
    int dst = edges[EE + e];
    int p = atomicAdd(&cursor[dst], 1);
    col[p] = edges[e];
}
// after fill: cursor[n] == row end; start = (n==0)?0:cursor[n-1]

// ---------------- fused gather + conv MLP + pool (single LDS buffer, cursor prefetch) ----------------
// block = 256 = 4 waves, 64 nodes. Gather: wave handles 16 nodes, 8 neighbor
// slots x 8 uint4-cols, register acc, shfl-fold, q==0 writes ldsB[feat*65+node].
// Row bounds prefetched per-lane (coalesced) and shfl'd in the loop.
// MLP: lane = node, wave = 16-feature segment (wave-uniform -> s_load weights);
// H reuses ldsB with a barrier. Epilogue: bf16 x write + segmented pool.
__global__ __launch_bounds__(256) void gconv_fused_kernel(
    const unsigned* __restrict__ xin, const int* __restrict__ cursor, const int* __restrict__ col,
    const float* __restrict__ W1s, const float* __restrict__ C1v,
    const float* __restrict__ W2s, const float* __restrict__ C2v,
    const int* __restrict__ batch,
    unsigned* __restrict__ xout, float* __restrict__ pooled)
{
    __shared__ float ldsB[64 * 65];   // gather acc [feat][node] -> later H
    int t = threadIdx.x;
    int lane = t & 63;
    int wv = t >> 6;
    int nbase = blockIdx.x << 6;

    // cursor prefetch: lane L holds start/end of node nbase+L (2 coalesced loads)
    int nL = nbase + lane;
    int myStart = 0, myEnd = 0;
    if (nL < NN) {
        myStart = (nL == 0) ? 0 : cursor[nL - 1];
        myEnd = cursor[nL];
    }

    // ---- gather phase (register accumulation; col from global) ----
    {
        int q = lane >> 3, c = lane & 7;
        const uint4* x4 = (const uint4*)xin;
        for (int s = 0; s < 16; s++) {
            int i = (wv << 4) + s;
            int n = nbase + i;
            if (n < NN) {
                int st = __shfl(myStart, i);
                int en = __shfl(myEnd, i);
                float acc[8];
                if (q == 0) {
                    uint4 u = x4[(long)n * 8 + c];
                    acc[0] = bf_lo(u.x); acc[1] = bf_hi(u.x);
                    acc[2] = bf_lo(u.y); acc[3] = bf_hi(u.y);
                    acc[4] = bf_lo(u.z); acc[5] = bf_hi(u.z);
                    acc[6] = bf_lo(u.w); acc[7] = bf_hi(u.w);
                } else {
#pragma unroll
                    for (int r = 0; r < 8; r++) acc[r] = 0.f;
                }
                for (int b2 = st + q; b2 < en; b2 += 8) {
                    int sc = col[b2];
                    uint4 u = x4[(long)sc * 8 + c];
                    acc[0] += bf_lo(u.x); acc[1] += bf_hi(u.x);
                    acc[2] += bf_lo(u.y); acc[3] += bf_hi(u.y);
                    acc[4] += bf_lo(u.z); acc[5] += bf_hi(u.z);
                    acc[6] += bf_lo(u.w); acc[7] += bf_hi(u.w);
                }
#pragma unroll
                for (int d = 8; d <= 32; d <<= 1) {
#pragma unroll
                    for (int r = 0; r < 8; r++) acc[r] += __shfl_xor(acc[r], d);
                }
                if (q == 0) {
                    int f = c << 3;
#pragma unroll
                    for (int r = 0; r < 8; r++) ldsB[(f + r) * 65 + i] = acc[r];
                }
            }
        }
    }
    __syncthreads();

    // ---- MLP layer 1 ----
    int wvu = __builtin_amdgcn_readfirstlane(wv);
    float a[16];
#pragma unroll
    for (int j = 0; j < 16; j++) a[j] = C1v[wvu * 16 + j];
#pragma unroll 4
    for (int k = 0; k < 64; k++) {
        float xk = ldsB[k * 65 + lane];
        const float* w = W1s + k * 64 + wvu * 16;
#pragma unroll
        for (int j = 0; j < 16; j++) a[j] += xk * w[j];
    }
    __syncthreads();   // all X reads done; safe to overwrite with H
#pragma unroll
    for (int j = 0; j < 16; j++) ldsB[(wvu * 16 + j) * 65 + lane] = fmaxf(a[j], 0.f);
    __syncthreads();

    // ---- MLP layer 2 ----
    float o[16];
#pragma unroll
    for (int j = 0; j < 16; j++) o[j] = C2v[wvu * 16 + j];
#pragma unroll 4
    for (int k = 0; k < 64; k++) {
        float hk = ldsB[k * 65 + lane];
        const float* w = W2s + k * 64 + wvu * 16;
#pragma unroll
        for (int j = 0; j < 16; j++) o[j] += hk * w[j];
    }
#pragma unroll
    for (int j = 0; j < 16; j++) o[j] = fmaxf(o[j], 0.f);

    int n = nbase + lane;
    if (n < NN) {
        unsigned u[8];
#pragma unroll
        for (int p = 0; p < 8; p++) u[p] = f2bf(o[2 * p]) | (f2bf(o[2 * p + 1]) << 16);
        uint4* xo = (uint4*)(xout + ((long)n << 5) + (wvu << 3));
        xo[0] = make_uint4(u[0], u[1], u[2], u[3]);
        xo[1] = make_uint4(u[4], u[5], u[6], u[7]);
    }

    // ---- fused pool: ballot-segmented reduction over sorted batch ----
    int bg = (n < NN) ? batch[n] : -1;
    int bprev = __shfl(bg, (lane == 0) ? 0 : lane - 1);
    bool bound = (lane == 0) || (bg != bprev);
    unsigned long long m = __ballot(bound);
    int p = 0;
    while (p < 64) {
        unsigned long long rest = (p < 63) ? (m & (~0ULL << (p + 1))) : 0ULL;
        int np = rest ? (__ffsll((long long)rest) - 1) : 64;
        int g = __shfl(bg, p);
        if (g >= 0) {
            bool in = (lane >= p) && (lane < np);
#pragma unroll
            for (int j = 0; j < 16; j++) {
                float v = in ? o[j] : 0.f;
                v += __shfl_xor(v, 1);  v += __shfl_xor(v, 2);
                v += __shfl_xor(v, 4);  v += __shfl_xor(v, 8);
                v += __shfl_xor(v, 16); v += __shfl_xor(v, 32);
                if (lane == p) unsafeAtomicAdd(&pooled[g * 64 + wvu * 16 + j], v);
            }
        }
        p = np;
    }
}

// ---------------- fused first MLP: embedding -> x (bf16) + stage-0 pool/cnt ----------------
// E-stage buffer reused for H (barriers between phases).
__global__ __launch_bounds__(256) void embed_fused_kernel(
    const int* __restrict__ node_ids, const float* __restrict__ emb,
    const float* __restrict__ W1s, const float* __restrict__ C1v,
    const float* __restrict__ W2s, const float* __restrict__ C2v,
    const int* __restrict__ batch,
    unsigned* __restrict__ xb, float* __restrict__ pooled, float* __restrict__ cnt)
{
    __shared__ float ldsB[64 * 129];   // E rows [node][k]; later H [feat][node]
    __shared__ int sh_nid[64];
    int t = threadIdx.x;
    int lane = t & 63;
    int wvu = __builtin_amdgcn_readfirstlane(t >> 6);
    int nbase = blockIdx.x << 6;
    if (t < 64) {
        int n0 = nbase + t;
        sh_nid[t] = (n0 < NN) ? node_ids[n0] : 0;
    }
    __syncthreads();
    for (int idx = t; idx < 8192; idx += 256) {
        int r = idx >> 7, c = idx & 127;
        ldsB[r * 129 + c] = emb[(long)sh_nid[r] * 128 + c];
    }
    __syncthreads();
    float a[16];
#pragma unroll
    for (int j = 0; j < 16; j++) a[j] = C1v[wvu * 16 + j];
#pragma unroll 4
    for (int k = 0; k < 128; k++) {
        float ek = ldsB[lane * 129 + k];
        const float* w = W1s + k * 64 + wvu * 16;
#pragma unroll
        for (int j = 0; j < 16; j++) a[j] += ek * w[j];
    }
    __syncthreads();   // E reads done; reuse buffer for H
#pragma unroll
    for (int j = 0; j < 16; j++) ldsB[(wvu * 16 + j) * 65 + lane] = fmaxf(a[j], 0.f);
    __syncthreads();
    float o[16];
#pragma unroll
    for (int j = 0; j < 16; j++) o[j] = C2v[wvu * 16 + j];
#pragma unroll 4
    for (int k = 0; k < 64; k++) {
        float hk = ldsB[k * 65 + lane];
        const float* w = W2s + k * 64 + wvu * 16;
#pragma unroll
        for (int j = 0; j < 16; j++) o[j] += hk * w[j];
    }
#pragma unroll
    for (int j = 0; j < 16; j++) o[j] = fmaxf(o[j], 0.f);

    int n = nbase + lane;
    if (n < NN) {
        unsigned u[8];
#pragma unroll
        for (int p = 0; p < 8; p++) u[p] = f2bf(o[2 * p]) | (f2bf(o[2 * p + 1]) << 16);
        uint4* xo = (uint4*)(xb + ((long)n << 5) + (wvu << 3));
        xo[0] = make_uint4(u[0], u[1], u[2], u[3]);
        xo[1] = make_uint4(u[4], u[5], u[6], u[7]);
    }

    int bg = (n < NN) ? batch[n] : -1;
    int bprev = __shfl(bg, (lane == 0) ? 0 : lane - 1);
    bool bound = (lane == 0) || (bg != bprev);
    unsigned long long m = __ballot(bound);
    int p = 0;
    while (p < 64) {
        unsigned long long rest = (p < 63) ? (m & (~0ULL << (p + 1))) : 0ULL;
        int np = rest ? (__ffsll((long long)rest) - 1) : 64;
        int g = __shfl(bg, p);
        if (g >= 0) {
            bool in = (lane >= p) && (lane < np);
#pragma unroll
            for (int j = 0; j < 16; j++) {
                float v = in ? o[j] : 0.f;
                v += __shfl_xor(v, 1);  v += __shfl_xor(v, 2);
                v += __shfl_xor(v, 4);  v += __shfl_xor(v, 8);
                v += __shfl_xor(v, 16); v += __shfl_xor(v, 32);
                if (lane == p) unsafeAtomicAdd(&pooled[g * 64 + wvu * 16 + j], v);
            }
            if (wvu == 0 && lane == p) unsafeAtomicAdd(&cnt[g], (float)(np - p));
        }
        p = np;
    }
}

// ---------------- readout + softmax ----------------
__global__ void final_kernel(
    const float* __restrict__ pooled, const float* __restrict__ cnt,
    const float* __restrict__ linW, const float* __restrict__ linb,
    float* __restrict__ outp)
{
    int g = threadIdx.x;
    if (g >= GG) return;
    float z0 = 0.f, z1 = 0.f;
    float c = cnt[g];
    for (int l = 0; l < 4; l++) {
        const float* p = pooled + (long)l * GG * 64 + (long)g * 64;
        const float* W = linW + l * 128;
        float bscale = (l == 0) ? c : 1.f;   // layer0 bias summed per node; others once
        float s0 = linb[l * 2 + 0] * bscale;
        float s1 = linb[l * 2 + 1] * bscale;
        for (int k = 0; k < 64; k++) {
            float pk = p[k];
            s0 += pk * W[k * 2 + 0];
            s1 += pk * W[k * 2 + 1];
        }
        z0 += s0; z1 += s1;
    }
    float mx = fmaxf(z0, z1);
    float e0 = expf(z0 - mx), e1 = expf(z1 - mx);
    float inv = 1.f / (e0 + e1);
    outp[g * 2 + 0] = e0 * inv;
    outp[g * 2 + 1] = e1 * inv;
}

extern "C" void kernel_launch(void* const* d_in, const int* in_sizes, int n_in,
                              void* d_out, int out_size, void* d_ws, size_t ws_size,
                              hipStream_t stream) {
    const int*   node_ids = (const int*)d_in[0];
    const int*   edges    = (const int*)d_in[1];
    const int*   batch    = (const int*)d_in[2];
    const float* emb      = (const float*)d_in[3];
    const float* fh_W1 = (const float*)d_in[4];
    const float* fh_b1 = (const float*)d_in[5];
    const float* fh_g1 = (const float*)d_in[6];
    const float* fh_bt1 = (const float*)d_in[7];
    const float* fh_m1 = (const float*)d_in[8];
    const float* fh_v1 = (const float*)d_in[9];
    const float* fh_W2 = (const float*)d_in[10];
    const float* fh_b2 = (const float*)d_in[11];
    const float* fh_g2 = (const float*)d_in[12];
    const float* fh_bt2 = (const float*)d_in[13];
    const float* fh_m2 = (const float*)d_in[14];
    const float* fh_v2 = (const float*)d_in[15];
    const float* cW1 = (const float*)d_in[16];
    const float* cb1 = (const float*)d_in[17];
    const float* cg1 = (const float*)d_in[18];
    const float* cbt1 = (const float*)d_in[19];
    const float* cm1 = (const float*)d_in[20];
    const float* cv1 = (const float*)d_in[21];
    const float* cW2 = (const float*)d_in[22];
    const float* cb2 = (const float*)d_in[23];
    const float* cg2 = (const float*)d_in[24];
    const float* cbt2 = (const float*)d_in[25];
    const float* cm2 = (const float*)d_in[26];
    const float* cv2 = (const float*)d_in[27];
    const float* linW = (const float*)d_in[28];
    const float* linb = (const float*)d_in[29];

    float*    ws     = (float*)d_ws;
    int*      cursor = (int*)(ws + CUR_OFF);
    int*      col    = (int*)(ws + COL_OFF);
    int*      bsum   = (int*)(ws + BSUM_OFF);
    unsigned* x0     = (unsigned*)(ws + X0_OFF);
    unsigned* x1     = (unsigned*)(ws + X1_OFF);

    prep_kernel<<<8, 256, 0, stream>>>(
        fh_W1, fh_b1, fh_g1, fh_bt1, fh_m1, fh_v1,
        fh_W2, fh_b2, fh_g2, fh_bt2, fh_m2, fh_v2,
        cW1, cb1, cg1, cbt1, cm1, cv1,
        cW2, cb2, cg2, cbt2, cm2, cv2, ws);

    hipMemsetAsync(ws + POOL_OFF, 0, (4L * GG * 64 + GG) * sizeof(float), stream);
    hipMemsetAsync(cursor, 0, NN * sizeof(int), stream);

    // CSR build (dst-indexed, single-pass fill)
    hist_kernel<<<(EE + 255) / 256, 256, 0, stream>>>(edges, cursor);
    scan_pass1<<<SCAN_NBLK, SCAN_BLK, 0, stream>>>(cursor, bsum);
    scan_pass2<<<1, 128, 0, stream>>>(bsum);
    scan_pass3<<<SCAN_NBLK, SCAN_BLK, 0, stream>>>(cursor, bsum);
    fill_kernel<<<(EE + 255) / 256, 256, 0, stream>>>(edges, cursor, col);

    const int FBLK = NT * 2;   // 1564 blocks (64 nodes each)

    embed_fused_kernel<<<FBLK, 256, 0, stream>>>(
        node_ids, emb, ws + WT1_OFF, ws + C1_OFF, ws + WT2_OFF, ws + C2_OFF,
        batch, x0, ws + POOL_OFF, ws + CNT_OFF);

    unsigned* xin = x0;
    unsigned* xout = x1;
    for (int l = 0; l < 3; l++) {
        gconv_fused_kernel<<<FBLK, 256, 0, stream>>>(
            xin, cursor, col,
            ws + WTC1_OFF + l * 4096, ws + CC1_OFF + l * 64,
            ws + WTC2_OFF + l * 4096, ws + CC2_OFF + l * 64,
            batch, xout, ws + POOL_OFF + (long)(l + 1) * GG * 64);
        unsigned* tmp = xin; xin = xout; xout = tmp;
    }

    final_kernel<<<1, 128, 0, stream>>>(
        ws + POOL_OFF, ws + CNT_OFF, linW, linb, (float*)d_out);
}

// Round 15
// 491.187 us; speedup vs baseline: 1.1880x; 1.0868x over previous
//
#include <hip/hip_runtime.h>
#include <hip/hip_bf16.h>

#define NN 100000
#define EE 1000000
#define GG 128
#define NT 782               // node tiles of 128 (782*128 = 100096)
#define BN_EPS 1e-5f
#define SLOTS 48             // fixed CSR row slots; Poisson(10) => P(deg>48) ~ 1e-18

// workspace float offsets
#define X0_OFF    0L          // x ping: packed bf16 [100096][64]
#define X1_OFF    3250000L    // x pong
#define COL2_OFF  6500000L    // slot CSR [100096][48] ints = 4,804,608
#define WT1_OFF   12806144L   // fh layer1 scaled cols [128][64]
#define C1_OFF    12814336L
#define WT2_OFF   12814400L   // fh layer2 scaled cols [64][64]
#define C2_OFF    12818496L
#define WTC1_OFF  12818560L   // conv layer1 x3
#define CC1_OFF   12830848L
#define WTC2_OFF  12831040L   // conv layer2 x3
#define CC2_OFF   12843328L
#define POOL_OFF  12843520L   // 4 stages * 128 * 64
#define CNT_OFF   12876288L   // 128
#define CUR_OFF   13876416L   // 100,000 ints (degree counters)
#define OVFC_OFF  13976416L   // 1 int (overflow count) - contiguous with CUR for one memset
#define OVF_OFF   13976420L   // overflow pairs (dst,src), cap 4096*2 ints

#define OVF_CAP 4096

__device__ __forceinline__ float bf_lo(unsigned v) { return __uint_as_float(v << 16); }
__device__ __forceinline__ float bf_hi(unsigned v) { return __uint_as_float(v & 0xffff0000u); }
__device__ __forceinline__ unsigned f2bf(float f) {
    unsigned b = __float_as_uint(f);
    return (b + 0x7fffu + ((b >> 16) & 1u)) >> 16;   // RNE
}

// ---------------- prep: fold BN scale into weight columns ----------------
__global__ void prep_kernel(
    const float* __restrict__ fh_W1, const float* __restrict__ fh_b1, const float* __restrict__ fh_g1,
    const float* __restrict__ fh_bt1, const float* __restrict__ fh_m1, const float* __restrict__ fh_v1,
    const float* __restrict__ fh_W2, const float* __restrict__ fh_b2, const float* __restrict__ fh_g2,
    const float* __restrict__ fh_bt2, const float* __restrict__ fh_m2, const float* __restrict__ fh_v2,
    const float* __restrict__ cW1, const float* __restrict__ cb1, const float* __restrict__ cg1,
    const float* __restrict__ cbt1, const float* __restrict__ cm1, const float* __restrict__ cv1,
    const float* __restrict__ cW2, const float* __restrict__ cb2, const float* __restrict__ cg2,
    const float* __restrict__ cbt2, const float* __restrict__ cm2, const float* __restrict__ cv2,
    float* __restrict__ ws)
{
    int job = blockIdx.x;
    const float *W, *b, *g, *bt, *m, *v;
    float *Wo, *Co;
    int K;
    if (job == 0) {
        W = fh_W1; b = fh_b1; g = fh_g1; bt = fh_bt1; m = fh_m1; v = fh_v1;
        Wo = ws + WT1_OFF; Co = ws + C1_OFF; K = 128;
    } else if (job == 1) {
        W = fh_W2; b = fh_b2; g = fh_g2; bt = fh_bt2; m = fh_m2; v = fh_v2;
        Wo = ws + WT2_OFF; Co = ws + C2_OFF; K = 64;
    } else if (job <= 4) {
        int l = job - 2;
        W = cW1 + l * 4096; b = cb1 + l * 64; g = cg1 + l * 64; bt = cbt1 + l * 64;
        m = cm1 + l * 64; v = cv1 + l * 64;
        Wo = ws + WTC1_OFF + l * 4096; Co = ws + CC1_OFF + l * 64; K = 64;
    } else {
        int l = job - 5;
        W = cW2 + l * 4096; b = cb2 + l * 64; g = cg2 + l * 64; bt = cbt2 + l * 64;
        m = cm2 + l * 64; v = cv2 + l * 64;
        Wo = ws + WTC2_OFF + l * 4096; Co = ws + CC2_OFF + l * 64; K = 64;
    }
    int tot = 64 * K;
    for (int i = threadIdx.x; i < tot; i += blockDim.x) {
        int j = i & 63;
        float s = g[j] * rsqrtf(v[j] + BN_EPS);
        Wo[i] = W[i] * s;   // [k][j] layout, scale column j
    }
    if (threadIdx.x < 64) {
        int j = threadIdx.x;
        float s = g[j] * rsqrtf(v[j] + BN_EPS);
        Co[j] = (b[j] - m[j]) * s + bt[j];
    }
}

// ---------------- slot-CSR fill: one pass, no hist/scan ----------------
__global__ __launch_bounds__(256) void fill2_kernel(
    const int* __restrict__ edges, int* __restrict__ cursor, int* __restrict__ col2,
    int* __restrict__ ovfCnt, int* __restrict__ ovf)
{
    int e = blockIdx.x * blockDim.x + threadIdx.x;
    if (e >= EE) return;
    int dst = edges[EE + e];
    int src = edges[e];
    int p = atomicAdd(&cursor[dst], 1);
    if (p < SLOTS) {
        col2[(long)dst * SLOTS + p] = src;
    } else {
        int q = atomicAdd(ovfCnt, 1);
        if (q < OVF_CAP) { ovf[2 * q] = dst; ovf[2 * q + 1] = src; }
    }
}
// after fill2: cursor[n] == raw degree of node n (may exceed SLOTS)

// ---------------- fused gather + conv MLP + pool (slot CSR, single LDS buffer) ----------------
// block = 256 = 4 waves, 64 nodes. Gather: wave handles 16 nodes, 8 neighbor
// slots x 8 uint4-cols, register acc, shfl-fold, q==0 writes ldsB[feat*65+node].
// MLP: lane = node, wave = 16-feature segment (wave-uniform -> s_load weights);
// H reuses ldsB with a barrier. Epilogue: bf16 x write + segmented pool.
__global__ __launch_bounds__(256) void gconv_fused_kernel(
    const unsigned* __restrict__ xin, const int* __restrict__ cursor, const int* __restrict__ col2,
    const int* __restrict__ ovfCnt, const int* __restrict__ ovf,
    const float* __restrict__ W1s, const float* __restrict__ C1v,
    const float* __restrict__ W2s, const float* __restrict__ C2v,
    const int* __restrict__ batch,
    unsigned* __restrict__ xout, float* __restrict__ pooled)
{
    __shared__ float ldsB[64 * 65];   // gather acc [feat][node] -> later H
    __shared__ int sh_no;
    int t = threadIdx.x;
    int lane = t & 63;
    int wv = t >> 6;
    int nbase = blockIdx.x << 6;
    if (t == 0) sh_no = *ovfCnt;

    // degree prefetch: lane L holds degree of node nbase+L (1 coalesced load)
    int nL = nbase + lane;
    int myDeg = 0;
    if (nL < NN) {
        myDeg = cursor[nL];
        if (myDeg > SLOTS) myDeg = SLOTS;
    }

    // ---- gather phase (register accumulation; col2 rows contiguous) ----
    {
        int q = lane >> 3, c = lane & 7;
        const uint4* x4 = (const uint4*)xin;
        for (int s = 0; s < 16; s++) {
            int i = (wv << 4) + s;
            int n = nbase + i;
            if (n < NN) {
                int deg = __shfl(myDeg, i);
                long cb = (long)n * SLOTS;
                float acc[8];
                if (q == 0) {
                    uint4 u = x4[(long)n * 8 + c];
                    acc[0] = bf_lo(u.x); acc[1] = bf_hi(u.x);
                    acc[2] = bf_lo(u.y); acc[3] = bf_hi(u.y);
                    acc[4] = bf_lo(u.z); acc[5] = bf_hi(u.z);
                    acc[6] = bf_lo(u.w); acc[7] = bf_hi(u.w);
                } else {
#pragma unroll
                    for (int r = 0; r < 8; r++) acc[r] = 0.f;
                }
                for (int b2 = q; b2 < deg; b2 += 8) {
                    int sc = col2[cb + b2];
                    uint4 u = x4[(long)sc * 8 + c];
                    acc[0] += bf_lo(u.x); acc[1] += bf_hi(u.x);
                    acc[2] += bf_lo(u.y); acc[3] += bf_hi(u.y);
                    acc[4] += bf_lo(u.z); acc[5] += bf_hi(u.z);
                    acc[6] += bf_lo(u.w); acc[7] += bf_hi(u.w);
                }
#pragma unroll
                for (int d = 8; d <= 32; d <<= 1) {
#pragma unroll
                    for (int r = 0; r < 8; r++) acc[r] += __shfl_xor(acc[r], d);
                }
                if (q == 0) {
                    int f = c << 3;
#pragma unroll
                    for (int r = 0; r < 8; r++) ldsB[(f + r) * 65 + i] = acc[r];
                }
            }
        }
    }
    __syncthreads();

    // ---- overflow edges (normally zero; serial on thread 0) ----
    if (sh_no > 0) {
        if (t == 0) {
            int no = sh_no; if (no > OVF_CAP) no = OVF_CAP;
            for (int i = 0; i < no; i++) {
                int dst = ovf[2 * i];
                if (dst >= nbase && dst < nbase + 64 && dst < NN) {
                    int src = ovf[2 * i + 1];
                    int loc = dst - nbase;
                    const unsigned* xr = xin + ((long)src << 5);
                    for (int f = 0; f < 32; f++) {
                        unsigned v = xr[f];
                        ldsB[(2 * f) * 65 + loc] += bf_lo(v);
                        ldsB[(2 * f + 1) * 65 + loc] += bf_hi(v);
                    }
                }
            }
        }
        __syncthreads();
    }

    // ---- MLP layer 1 ----
    int wvu = __builtin_amdgcn_readfirstlane(wv);
    float a[16];
#pragma unroll
    for (int j = 0; j < 16; j++) a[j] = C1v[wvu * 16 + j];
#pragma unroll 4
    for (int k = 0; k < 64; k++) {
        float xk = ldsB[k * 65 + lane];
        const float* w = W1s + k * 64 + wvu * 16;
#pragma unroll
        for (int j = 0; j < 16; j++) a[j] += xk * w[j];
    }
    __syncthreads();   // all X reads done; safe to overwrite with H
#pragma unroll
    for (int j = 0; j < 16; j++) ldsB[(wvu * 16 + j) * 65 + lane] = fmaxf(a[j], 0.f);
    __syncthreads();

    // ---- MLP layer 2 ----
    float o[16];
#pragma unroll
    for (int j = 0; j < 16; j++) o[j] = C2v[wvu * 16 + j];
#pragma unroll 4
    for (int k = 0; k < 64; k++) {
        float hk = ldsB[k * 65 + lane];
        const float* w = W2s + k * 64 + wvu * 16;
#pragma unroll
        for (int j = 0; j < 16; j++) o[j] += hk * w[j];
    }
#pragma unroll
    for (int j = 0; j < 16; j++) o[j] = fmaxf(o[j], 0.f);

    int n = nbase + lane;
    if (n < NN) {
        unsigned u[8];
#pragma unroll
        for (int p = 0; p < 8; p++) u[p] = f2bf(o[2 * p]) | (f2bf(o[2 * p + 1]) << 16);
        uint4* xo = (uint4*)(xout + ((long)n << 5) + (wvu << 3));
        xo[0] = make_uint4(u[0], u[1], u[2], u[3]);
        xo[1] = make_uint4(u[4], u[5], u[6], u[7]);
    }

    // ---- fused pool: ballot-segmented reduction over sorted batch ----
    int bg = (n < NN) ? batch[n] : -1;
    int bprev = __shfl(bg, (lane == 0) ? 0 : lane - 1);
    bool bound = (lane == 0) || (bg != bprev);
    unsigned long long m = __ballot(bound);
    int p = 0;
    while (p < 64) {
        unsigned long long rest = (p < 63) ? (m & (~0ULL << (p + 1))) : 0ULL;
        int np = rest ? (__ffsll((long long)rest) - 1) : 64;
        int g = __shfl(bg, p);
        if (g >= 0) {
            bool in = (lane >= p) && (lane < np);
#pragma unroll
            for (int j = 0; j < 16; j++) {
                float v = in ? o[j] : 0.f;
                v += __shfl_xor(v, 1);  v += __shfl_xor(v, 2);
                v += __shfl_xor(v, 4);  v += __shfl_xor(v, 8);
                v += __shfl_xor(v, 16); v += __shfl_xor(v, 32);
                if (lane == p) unsafeAtomicAdd(&pooled[g * 64 + wvu * 16 + j], v);
            }
        }
        p = np;
    }
}

// ---------------- fused first MLP: embedding -> x (bf16) + stage-0 pool/cnt ----------------
// E-stage buffer reused for H (barriers between phases).
__global__ __launch_bounds__(256) void embed_fused_kernel(
    const int* __restrict__ node_ids, const float* __restrict__ emb,
    const float* __restrict__ W1s, const float* __restrict__ C1v,
    const float* __restrict__ W2s, const float* __restrict__ C2v,
    const int* __restrict__ batch,
    unsigned* __restrict__ xb, float* __restrict__ pooled, float* __restrict__ cnt)
{
    __shared__ float ldsB[64 * 129];   // E rows [node][k]; later H [feat][node]
    __shared__ int sh_nid[64];
    int t = threadIdx.x;
    int lane = t & 63;
    int wvu = __builtin_amdgcn_readfirstlane(t >> 6);
    int nbase = blockIdx.x << 6;
    if (t < 64) {
        int n0 = nbase + t;
        sh_nid[t] = (n0 < NN) ? node_ids[n0] : 0;
    }
    __syncthreads();
    for (int idx = t; idx < 8192; idx += 256) {
        int r = idx >> 7, c = idx & 127;
        ldsB[r * 129 + c] = emb[(long)sh_nid[r] * 128 + c];
    }
    __syncthreads();
    float a[16];
#pragma unroll
    for (int j = 0; j < 16; j++) a[j] = C1v[wvu * 16 + j];
#pragma unroll 4
    for (int k = 0; k < 128; k++) {
        float ek = ldsB[lane * 129 + k];
        const float* w = W1s + k * 64 + wvu * 16;
#pragma unroll
        for (int j = 0; j < 16; j++) a[j] += ek * w[j];
    }
    __syncthreads();   // E reads done; reuse buffer for H
#pragma unroll
    for (int j = 0; j < 16; j++) ldsB[(wvu * 16 + j) * 65 + lane] = fmaxf(a[j], 0.f);
    __syncthreads();
    float o[16];
#pragma unroll
    for (int j = 0; j < 16; j++) o[j] = C2v[wvu * 16 + j];
#pragma unroll 4
    for (int k = 0; k < 64; k++) {
        float hk = ldsB[k * 65 + lane];
        const float* w = W2s + k * 64 + wvu * 16;
#pragma unroll
        for (int j = 0; j < 16; j++) o[j] += hk * w[j];
    }
#pragma unroll
    for (int j = 0; j < 16; j++) o[j] = fmaxf(o[j], 0.f);

    int n = nbase + lane;
    if (n < NN) {
        unsigned u[8];
#pragma unroll
        for (int p = 0; p < 8; p++) u[p] = f2bf(o[2 * p]) | (f2bf(o[2 * p + 1]) << 16);
        uint4* xo = (uint4*)(xb + ((long)n << 5) + (wvu << 3));
        xo[0] = make_uint4(u[0], u[1], u[2], u[3]);
        xo[1] = make_uint4(u[4], u[5], u[6], u[7]);
    }

    int bg = (n < NN) ? batch[n] : -1;
    int bprev = __shfl(bg, (lane == 0) ? 0 : lane - 1);
    bool bound = (lane == 0) || (bg != bprev);
    unsigned long long m = __ballot(bound);
    int p = 0;
    while (p < 64) {
        unsigned long long rest = (p < 63) ? (m & (~0ULL << (p + 1))) : 0ULL;
        int np = rest ? (__ffsll((long long)rest) - 1) : 64;
        int g = __shfl(bg, p);
        if (g >= 0) {
            bool in = (lane >= p) && (lane < np);
#pragma unroll
            for (int j = 0; j < 16; j++) {
                float v = in ? o[j] : 0.f;
                v += __shfl_xor(v, 1);  v += __shfl_xor(v, 2);
                v += __shfl_xor(v, 4);  v += __shfl_xor(v, 8);
                v += __shfl_xor(v, 16); v += __shfl_xor(v, 32);
                if (lane == p) unsafeAtomicAdd(&pooled[g * 64 + wvu * 16 + j], v);
            }
            if (wvu == 0 && lane == p) unsafeAtomicAdd(&cnt[g], (float)(np - p));
        }
        p = np;
    }
}

// ---------------- readout + softmax ----------------
__global__ void final_kernel(
    const float* __restrict__ pooled, const float* __restrict__ cnt,
    const float* __restrict__ linW, const float* __restrict__ linb,
    float* __restrict__ outp)
{
    int g = threadIdx.x;
    if (g >= GG) return;
    float z0 = 0.f, z1 = 0.f;
    float c = cnt[g];
    for (int l = 0; l < 4; l++) {
        const float* p = pooled + (long)l * GG * 64 + (long)g * 64;
        const float* W = linW + l * 128;
        float bscale = (l == 0) ? c : 1.f;   // layer0 bias summed per node; others once
        float s0 = linb[l * 2 + 0] * bscale;
        float s1 = linb[l * 2 + 1] * bscale;
        for (int k = 0; k < 64; k++) {
            float pk = p[k];
            s0 += pk * W[k * 2 + 0];
            s1 += pk * W[k * 2 + 1];
        }
        z0 += s0; z1 += s1;
    }
    float mx = fmaxf(z0, z1);
    float e0 = expf(z0 - mx), e1 = expf(z1 - mx);
    float inv = 1.f / (e0 + e1);
    outp[g * 2 + 0] = e0 * inv;
    outp[g * 2 + 1] = e1 * inv;
}

extern "C" void kernel_launch(void* const* d_in, const int* in_sizes, int n_in,
                              void* d_out, int out_size, void* d_ws, size_t ws_size,
                              hipStream_t stream) {
    const int*   node_ids = (const int*)d_in[0];
    const int*   edges    = (const int*)d_in[1];
    const int*   batch    = (const int*)d_in[2];
    const float* emb      = (const float*)d_in[3];
    const float* fh_W1 = (const float*)d_in[4];
    const float* fh_b1 = (const float*)d_in[5];
    const float* fh_g1 = (const float*)d_in[6];
    const float* fh_bt1 = (const float*)d_in[7];
    const float* fh_m1 = (const float*)d_in[8];
    const float* fh_v1 = (const float*)d_in[9];
    const float* fh_W2 = (const float*)d_in[10];
    const float* fh_b2 = (const float*)d_in[11];
    const float* fh_g2 = (const float*)d_in[12];
    const float* fh_bt2 = (const float*)d_in[13];
    const float* fh_m2 = (const float*)d_in[14];
    const float* fh_v2 = (const float*)d_in[15];
    const float* cW1 = (const float*)d_in[16];
    const float* cb1 = (const float*)d_in[17];
    const float* cg1 = (const float*)d_in[18];
    const float* cbt1 = (const float*)d_in[19];
    const float* cm1 = (const float*)d_in[20];
    const float* cv1 = (const float*)d_in[21];
    const float* cW2 = (const float*)d_in[22];
    const float* cb2 = (const float*)d_in[23];
    const float* cg2 = (const float*)d_in[24];
    const float* cbt2 = (const float*)d_in[25];
    const float* cm2 = (const float*)d_in[26];
    const float* cv2 = (const float*)d_in[27];
    const float* linW = (const float*)d_in[28];
    const float* linb = (const float*)d_in[29];

    float*    ws     = (float*)d_ws;
    int*      cursor = (int*)(ws + CUR_OFF);
    int*      col2   = (int*)(ws + COL2_OFF);
    int*      ovfCnt = (int*)(ws + OVFC_OFF);
    int*      ovf    = (int*)(ws + OVF_OFF);
    unsigned* x0     = (unsigned*)(ws + X0_OFF);
    unsigned* x1     = (unsigned*)(ws + X1_OFF);

    prep_kernel<<<8, 256, 0, stream>>>(
        fh_W1, fh_b1, fh_g1, fh_bt1, fh_m1, fh_v1,
        fh_W2, fh_b2, fh_g2, fh_bt2, fh_m2, fh_v2,
        cW1, cb1, cg1, cbt1, cm1, cv1,
        cW2, cb2, cg2, cbt2, cm2, cv2, ws);

    hipMemsetAsync(ws + POOL_OFF, 0, (4L * GG * 64 + GG) * sizeof(float), stream);
    hipMemsetAsync(cursor, 0, (NN + 1) * sizeof(int) + (CUR_OFF + NN + 1 == OVFC_OFF + 1 ? 0 : 0), stream);
    hipMemsetAsync(ovfCnt, 0, sizeof(int), stream);

    // slot-CSR build: single pass, no hist/scan
    fill2_kernel<<<(EE + 255) / 256, 256, 0, stream>>>(edges, cursor, col2, ovfCnt, ovf);

    const int FBLK = NT * 2;   // 1564 blocks (64 nodes each)

    embed_fused_kernel<<<FBLK, 256, 0, stream>>>(
        node_ids, emb, ws + WT1_OFF, ws + C1_OFF, ws + WT2_OFF, ws + C2_OFF,
        batch, x0, ws + POOL_OFF, ws + CNT_OFF);

    unsigned* xin = x0;
    unsigned* xout = x1;
    for (int l = 0; l < 3; l++) {
        gconv_fused_kernel<<<FBLK, 256, 0, stream>>>(
            xin, cursor, col2, ovfCnt, ovf,
            ws + WTC1_OFF + l * 4096, ws + CC1_OFF + l * 64,
            ws + WTC2_OFF + l * 4096, ws + CC2_OFF + l * 64,
            batch, xout, ws + POOL_OFF + (long)(l + 1) * GG * 64);
        unsigned* tmp = xin; xin = xout; xout = tmp;
    }

    final_kernel<<<1, 128, 0, stream>>>(
        ws + POOL_OFF, ws + CNT_OFF, linW, linb, (float*)d_out);
}

// Round 16
// 480.442 us; speedup vs baseline: 1.2146x; 1.0224x over previous
//
#include <hip/hip_runtime.h>
#include <hip/hip_bf16.h>

#define NN 100000
#define EE 1000000
#define GG 128
#define NT 782               // node tiles of 128 (782*128 = 100096)
#define BN_EPS 1e-5f
#define SLOTS 48             // fixed CSR row slots; Poisson(10) => P(deg>48) ~ 1e-18
#define NFILL ((EE + 255) / 256)   // 3907 fill blocks

// workspace float offsets
#define X0_OFF    0L          // x ping: packed bf16 [100096][64]
#define X1_OFF    3250000L    // x pong
#define COL2_OFF  6500000L    // slot CSR [100096][48] ints
#define WT1_OFF   12806144L   // fh layer1 scaled cols [128][64]
#define C1_OFF    12814336L
#define WT2_OFF   12814400L   // fh layer2 scaled cols [64][64]
#define C2_OFF    12818496L
#define WTC1_OFF  12818560L   // conv layer1 x3
#define CC1_OFF   12830848L
#define WTC2_OFF  12831040L   // conv layer2 x3
#define CC2_OFF   12843328L
#define POOL_OFF  12843520L   // 4 stages * 128 * 64 (+cnt contiguous)
#define CNT_OFF   12876288L   // 128
#define CUR_OFF   13876416L   // 100,000 ints (degree counters)
#define OVFC_OFF  13976416L   // 1 int (contiguous after cursor)
#define OVF_OFF   13976420L   // overflow pairs (dst,src)

#define OVF_CAP 4096
#define ZERO_INTS (NN + 1 + 4 * GG * 64 + GG)   // cursor+ovfCnt then pooled+cnt
#define ZBLK ((ZERO_INTS + 255) / 256)           // 520

__device__ __forceinline__ float bf_lo(unsigned v) { return __uint_as_float(v << 16); }
__device__ __forceinline__ float bf_hi(unsigned v) { return __uint_as_float(v & 0xffff0000u); }
__device__ __forceinline__ unsigned f2bf(float f) {
    unsigned b = __float_as_uint(f);
    return (b + 0x7fffu + ((b >> 16) & 1u)) >> 16;   // RNE
}

// ---------------- prep: fold BN into weights + zero cursor/ovf/pooled/cnt ----------------
__global__ void prep_kernel(
    const float* __restrict__ fh_W1, const float* __restrict__ fh_b1, const float* __restrict__ fh_g1,
    const float* __restrict__ fh_bt1, const float* __restrict__ fh_m1, const float* __restrict__ fh_v1,
    const float* __restrict__ fh_W2, const float* __restrict__ fh_b2, const float* __restrict__ fh_g2,
    const float* __restrict__ fh_bt2, const float* __restrict__ fh_m2, const float* __restrict__ fh_v2,
    const float* __restrict__ cW1, const float* __restrict__ cb1, const float* __restrict__ cg1,
    const float* __restrict__ cbt1, const float* __restrict__ cm1, const float* __restrict__ cv1,
    const float* __restrict__ cW2, const float* __restrict__ cb2, const float* __restrict__ cg2,
    const float* __restrict__ cbt2, const float* __restrict__ cm2, const float* __restrict__ cv2,
    float* __restrict__ ws)
{
    int job = blockIdx.x;
    if (job >= 8) {
        long idx = (long)(job - 8) * 256 + threadIdx.x;
        if (idx < NN + 1) {
            ((int*)(ws + CUR_OFF))[idx] = 0;            // cursor + ovfCnt (contiguous)
        } else {
            long i2 = idx - (NN + 1);
            if (i2 < 4L * GG * 64 + GG) (ws + POOL_OFF)[i2] = 0.f;   // pooled + cnt
        }
        return;
    }
    const float *W, *b, *g, *bt, *m, *v;
    float *Wo, *Co;
    int K;
    if (job == 0) {
        W = fh_W1; b = fh_b1; g = fh_g1; bt = fh_bt1; m = fh_m1; v = fh_v1;
        Wo = ws + WT1_OFF; Co = ws + C1_OFF; K = 128;
    } else if (job == 1) {
        W = fh_W2; b = fh_b2; g = fh_g2; bt = fh_bt2; m = fh_m2; v = fh_v2;
        Wo = ws + WT2_OFF; Co = ws + C2_OFF; K = 64;
    } else if (job <= 4) {
        int l = job - 2;
        W = cW1 + l * 4096; b = cb1 + l * 64; g = cg1 + l * 64; bt = cbt1 + l * 64;
        m = cm1 + l * 64; v = cv1 + l * 64;
        Wo = ws + WTC1_OFF + l * 4096; Co = ws + CC1_OFF + l * 64; K = 64;
    } else {
        int l = job - 5;
        W = cW2 + l * 4096; b = cb2 + l * 64; g = cg2 + l * 64; bt = cbt2 + l * 64;
        m = cm2 + l * 64; v = cv2 + l * 64;
        Wo = ws + WTC2_OFF + l * 4096; Co = ws + CC2_OFF + l * 64; K = 64;
    }
    int tot = 64 * K;
    for (int i = threadIdx.x; i < tot; i += blockDim.x) {
        int j = i & 63;
        float s = g[j] * rsqrtf(v[j] + BN_EPS);
        Wo[i] = W[i] * s;   // [k][j] layout, scale column j
    }
    if (threadIdx.x < 64) {
        int j = threadIdx.x;
        float s = g[j] * rsqrtf(v[j] + BN_EPS);
        Co[j] = (b[j] - m[j]) * s + bt[j];
    }
}

// ---------------- prologue: slot-CSR fill (blocks < NFILL) + embed MLP (rest) ----------------
// Fill path is latency-bound (atomics, no VALU); embed path is VALU-bound.
// Co-scheduling in one dispatch overlaps them. LDS kept at 16.9 KB via
// two-half E staging so fill blocks aren't LDS-starved.
__global__ __launch_bounds__(256) void prologue_kernel(
    const int* __restrict__ edges, int* __restrict__ cursor, int* __restrict__ col2,
    int* __restrict__ ovfCnt, int* __restrict__ ovf,
    const int* __restrict__ node_ids, const float* __restrict__ emb,
    const float* __restrict__ W1s, const float* __restrict__ C1v,
    const float* __restrict__ W2s, const float* __restrict__ C2v,
    const int* __restrict__ batch,
    unsigned* __restrict__ xb, float* __restrict__ pooled, float* __restrict__ cnt)
{
    __shared__ float ldsB[64 * 65];   // E half [node][k] -> later H [feat][node]
    __shared__ int sh_nid[64];
    int t = threadIdx.x;

    if (blockIdx.x < NFILL) {
        // ---- fill path ----
        int e = blockIdx.x * 256 + t;
        if (e < EE) {
            int dst = edges[EE + e];
            int src = edges[e];
            int p = atomicAdd(&cursor[dst], 1);
            if (p < SLOTS) {
                col2[(long)dst * SLOTS + p] = src;
            } else {
                int q = atomicAdd(ovfCnt, 1);
                if (q < OVF_CAP) { ovf[2 * q] = dst; ovf[2 * q + 1] = src; }
            }
        }
        return;
    }

    // ---- embed path ----
    int lane = t & 63;
    int wvu = __builtin_amdgcn_readfirstlane(t >> 6);
    int nbase = (int)(blockIdx.x - NFILL) << 6;
    if (t < 64) {
        int n0 = nbase + t;
        sh_nid[t] = (n0 < NN) ? node_ids[n0] : 0;
    }
    __syncthreads();

    float a[16];
#pragma unroll
    for (int j = 0; j < 16; j++) a[j] = C1v[wvu * 16 + j];

#pragma unroll
    for (int half = 0; half < 2; half++) {
        // stage 64 nodes x 64 feats of emb (coalesced 256B per row)
        for (int idx = t; idx < 4096; idx += 256) {
            int r = idx >> 6, c = idx & 63;
            ldsB[r * 65 + c] = emb[(long)sh_nid[r] * 128 + half * 64 + c];
        }
        __syncthreads();
#pragma unroll 4
        for (int k = 0; k < 64; k++) {
            float ek = ldsB[lane * 65 + k];
            const float* w = W1s + (half * 64 + k) * 64 + wvu * 16;
#pragma unroll
            for (int j = 0; j < 16; j++) a[j] += ek * w[j];
        }
        __syncthreads();   // reads done before next half overwrites
    }

#pragma unroll
    for (int j = 0; j < 16; j++) ldsB[(wvu * 16 + j) * 65 + lane] = fmaxf(a[j], 0.f);
    __syncthreads();
    float o[16];
#pragma unroll
    for (int j = 0; j < 16; j++) o[j] = C2v[wvu * 16 + j];
#pragma unroll 4
    for (int k = 0; k < 64; k++) {
        float hk = ldsB[k * 65 + lane];
        const float* w = W2s + k * 64 + wvu * 16;
#pragma unroll
        for (int j = 0; j < 16; j++) o[j] += hk * w[j];
    }
#pragma unroll
    for (int j = 0; j < 16; j++) o[j] = fmaxf(o[j], 0.f);

    int n = nbase + lane;
    if (n < NN) {
        unsigned u[8];
#pragma unroll
        for (int p = 0; p < 8; p++) u[p] = f2bf(o[2 * p]) | (f2bf(o[2 * p + 1]) << 16);
        uint4* xo = (uint4*)(xb + ((long)n << 5) + (wvu << 3));
        xo[0] = make_uint4(u[0], u[1], u[2], u[3]);
        xo[1] = make_uint4(u[4], u[5], u[6], u[7]);
    }

    int bg = (n < NN) ? batch[n] : -1;
    int bprev = __shfl(bg, (lane == 0) ? 0 : lane - 1);
    bool bound = (lane == 0) || (bg != bprev);
    unsigned long long m = __ballot(bound);
    int p = 0;
    while (p < 64) {
        unsigned long long rest = (p < 63) ? (m & (~0ULL << (p + 1))) : 0ULL;
        int np = rest ? (__ffsll((long long)rest) - 1) : 64;
        int g = __shfl(bg, p);
        if (g >= 0) {
            bool in = (lane >= p) && (lane < np);
#pragma unroll
            for (int j = 0; j < 16; j++) {
                float v = in ? o[j] : 0.f;
                v += __shfl_xor(v, 1);  v += __shfl_xor(v, 2);
                v += __shfl_xor(v, 4);  v += __shfl_xor(v, 8);
                v += __shfl_xor(v, 16); v += __shfl_xor(v, 32);
                if (lane == p) unsafeAtomicAdd(&pooled[g * 64 + wvu * 16 + j], v);
            }
            if (wvu == 0 && lane == p) unsafeAtomicAdd(&cnt[g], (float)(np - p));
        }
        p = np;
    }
}

// ---------------- fused gather + conv MLP + pool (slot CSR, single LDS buffer) ----------------
__global__ __launch_bounds__(256) void gconv_fused_kernel(
    const unsigned* __restrict__ xin, const int* __restrict__ cursor, const int* __restrict__ col2,
    const int* __restrict__ ovfCnt, const int* __restrict__ ovf,
    const float* __restrict__ W1s, const float* __restrict__ C1v,
    const float* __restrict__ W2s, const float* __restrict__ C2v,
    const int* __restrict__ batch,
    unsigned* __restrict__ xout, float* __restrict__ pooled)
{
    __shared__ float ldsB[64 * 65];   // gather acc [feat][node] -> later H
    __shared__ int sh_no;
    int t = threadIdx.x;
    int lane = t & 63;
    int wv = t >> 6;
    int nbase = blockIdx.x << 6;
    if (t == 0) sh_no = *ovfCnt;

    int nL = nbase + lane;
    int myDeg = 0;
    if (nL < NN) {
        myDeg = cursor[nL];
        if (myDeg > SLOTS) myDeg = SLOTS;
    }

    {
        int q = lane >> 3, c = lane & 7;
        const uint4* x4 = (const uint4*)xin;
        for (int s = 0; s < 16; s++) {
            int i = (wv << 4) + s;
            int n = nbase + i;
            if (n < NN) {
                int deg = __shfl(myDeg, i);
                long cb = (long)n * SLOTS;
                float acc[8];
                if (q == 0) {
                    uint4 u = x4[(long)n * 8 + c];
                    acc[0] = bf_lo(u.x); acc[1] = bf_hi(u.x);
                    acc[2] = bf_lo(u.y); acc[3] = bf_hi(u.y);
                    acc[4] = bf_lo(u.z); acc[5] = bf_hi(u.z);
                    acc[6] = bf_lo(u.w); acc[7] = bf_hi(u.w);
                } else {
#pragma unroll
                    for (int r = 0; r < 8; r++) acc[r] = 0.f;
                }
                for (int b2 = q; b2 < deg; b2 += 8) {
                    int sc = col2[cb + b2];
                    uint4 u = x4[(long)sc * 8 + c];
                    acc[0] += bf_lo(u.x); acc[1] += bf_hi(u.x);
                    acc[2] += bf_lo(u.y); acc[3] += bf_hi(u.y);
                    acc[4] += bf_lo(u.z); acc[5] += bf_hi(u.z);
                    acc[6] += bf_lo(u.w); acc[7] += bf_hi(u.w);
                }
#pragma unroll
                for (int d = 8; d <= 32; d <<= 1) {
#pragma unroll
                    for (int r = 0; r < 8; r++) acc[r] += __shfl_xor(acc[r], d);
                }
                if (q == 0) {
                    int f = c << 3;
#pragma unroll
                    for (int r = 0; r < 8; r++) ldsB[(f + r) * 65 + i] = acc[r];
                }
            }
        }
    }
    __syncthreads();

    if (sh_no > 0) {
        if (t == 0) {
            int no = sh_no; if (no > OVF_CAP) no = OVF_CAP;
            for (int i = 0; i < no; i++) {
                int dst = ovf[2 * i];
                if (dst >= nbase && dst < nbase + 64 && dst < NN) {
                    int src = ovf[2 * i + 1];
                    int loc = dst - nbase;
                    const unsigned* xr = xin + ((long)src << 5);
                    for (int f = 0; f < 32; f++) {
                        unsigned v = xr[f];
                        ldsB[(2 * f) * 65 + loc] += bf_lo(v);
                        ldsB[(2 * f + 1) * 65 + loc] += bf_hi(v);
                    }
                }
            }
        }
        __syncthreads();
    }

    int wvu = __builtin_amdgcn_readfirstlane(wv);
    float a[16];
#pragma unroll
    for (int j = 0; j < 16; j++) a[j] = C1v[wvu * 16 + j];
#pragma unroll 4
    for (int k = 0; k < 64; k++) {
        float xk = ldsB[k * 65 + lane];
        const float* w = W1s + k * 64 + wvu * 16;
#pragma unroll
        for (int j = 0; j < 16; j++) a[j] += xk * w[j];
    }
    __syncthreads();
#pragma unroll
    for (int j = 0; j < 16; j++) ldsB[(wvu * 16 + j) * 65 + lane] = fmaxf(a[j], 0.f);
    __syncthreads();

    float o[16];
#pragma unroll
    for (int j = 0; j < 16; j++) o[j] = C2v[wvu * 16 + j];
#pragma unroll 4
    for (int k = 0; k < 64; k++) {
        float hk = ldsB[k * 65 + lane];
        const float* w = W2s + k * 64 + wvu * 16;
#pragma unroll
        for (int j = 0; j < 16; j++) o[j] += hk * w[j];
    }
#pragma unroll
    for (int j = 0; j < 16; j++) o[j] = fmaxf(o[j], 0.f);

    int n = nbase + lane;
    if (n < NN) {
        unsigned u[8];
#pragma unroll
        for (int p = 0; p < 8; p++) u[p] = f2bf(o[2 * p]) | (f2bf(o[2 * p + 1]) << 16);
        uint4* xo = (uint4*)(xout + ((long)n << 5) + (wvu << 3));
        xo[0] = make_uint4(u[0], u[1], u[2], u[3]);
        xo[1] = make_uint4(u[4], u[5], u[6], u[7]);
    }

    int bg = (n < NN) ? batch[n] : -1;
    int bprev = __shfl(bg, (lane == 0) ? 0 : lane - 1);
    bool bound = (lane == 0) || (bg != bprev);
    unsigned long long m = __ballot(bound);
    int p = 0;
    while (p < 64) {
        unsigned long long rest = (p < 63) ? (m & (~0ULL << (p + 1))) : 0ULL;
        int np = rest ? (__ffsll((long long)rest) - 1) : 64;
        int g = __shfl(bg, p);
        if (g >= 0) {
            bool in = (lane >= p) && (lane < np);
#pragma unroll
            for (int j = 0; j < 16; j++) {
                float v = in ? o[j] : 0.f;
                v += __shfl_xor(v, 1);  v += __shfl_xor(v, 2);
                v += __shfl_xor(v, 4);  v += __shfl_xor(v, 8);
                v += __shfl_xor(v, 16); v += __shfl_xor(v, 32);
                if (lane == p) unsafeAtomicAdd(&pooled[g * 64 + wvu * 16 + j], v);
            }
        }
        p = np;
    }
}

// ---------------- readout + softmax ----------------
__global__ void final_kernel(
    const float* __restrict__ pooled, const float* __restrict__ cnt,
    const float* __restrict__ linW, const float* __restrict__ linb,
    float* __restrict__ outp)
{
    int g = threadIdx.x;
    if (g >= GG) return;
    float z0 = 0.f, z1 = 0.f;
    float c = cnt[g];
    for (int l = 0; l < 4; l++) {
        const float* p = pooled + (long)l * GG * 64 + (long)g * 64;
        const float* W = linW + l * 128;
        float bscale = (l == 0) ? c : 1.f;
        float s0 = linb[l * 2 + 0] * bscale;
        float s1 = linb[l * 2 + 1] * bscale;
        for (int k = 0; k < 64; k++) {
            float pk = p[k];
            s0 += pk * W[k * 2 + 0];
            s1 += pk * W[k * 2 + 1];
        }
        z0 += s0; z1 += s1;
    }
    float mx = fmaxf(z0, z1);
    float e0 = expf(z0 - mx), e1 = expf(z1 - mx);
    float inv = 1.f / (e0 + e1);
    outp[g * 2 + 0] = e0 * inv;
    outp[g * 2 + 1] = e1 * inv;
}

extern "C" void kernel_launch(void* const* d_in, const int* in_sizes, int n_in,
                              void* d_out, int out_size, void* d_ws, size_t ws_size,
                              hipStream_t stream) {
    const int*   node_ids = (const int*)d_in[0];
    const int*   edges    = (const int*)d_in[1];
    const int*   batch    = (const int*)d_in[2];
    const float* emb      = (const float*)d_in[3];
    const float* fh_W1 = (const float*)d_in[4];
    const float* fh_b1 = (const float*)d_in[5];
    const float* fh_g1 = (const float*)d_in[6];
    const float* fh_bt1 = (const float*)d_in[7];
    const float* fh_m1 = (const float*)d_in[8];
    const float* fh_v1 = (const float*)d_in[9];
    const float* fh_W2 = (const float*)d_in[10];
    const float* fh_b2 = (const float*)d_in[11];
    const float* fh_g2 = (const float*)d_in[12];
    const float* fh_bt2 = (const float*)d_in[13];
    const float* fh_m2 = (const float*)d_in[14];
    const float* fh_v2 = (const float*)d_in[15];
    const float* cW1 = (const float*)d_in[16];
    const float* cb1 = (const float*)d_in[17];
    const float* cg1 = (const float*)d_in[18];
    const float* cbt1 = (const float*)d_in[19];
    const float* cm1 = (const float*)d_in[20];
    const float* cv1 = (const float*)d_in[21];
    const float* cW2 = (const float*)d_in[22];
    const float* cb2 = (const float*)d_in[23];
    const float* cg2 = (const float*)d_in[24];
    const float* cbt2 = (const float*)d_in[25];
    const float* cm2 = (const float*)d_in[26];
    const float* cv2 = (const float*)d_in[27];
    const float* linW = (const float*)d_in[28];
    const float* linb = (const float*)d_in[29];

    float*    ws     = (float*)d_ws;
    int*      cursor = (int*)(ws + CUR_OFF);
    int*      col2   = (int*)(ws + COL2_OFF);
    int*      ovfCnt = (int*)(ws + OVFC_OFF);
    int*      ovf    = (int*)(ws + OVF_OFF);
    unsigned* x0     = (unsigned*)(ws + X0_OFF);
    unsigned* x1     = (unsigned*)(ws + X1_OFF);

    // prep: weight folding (8 blocks) + zeroing (ZBLK blocks)
    prep_kernel<<<8 + ZBLK, 256, 0, stream>>>(
        fh_W1, fh_b1, fh_g1, fh_bt1, fh_m1, fh_v1,
        fh_W2, fh_b2, fh_g2, fh_bt2, fh_m2, fh_v2,
        cW1, cb1, cg1, cbt1, cm1, cv1,
        cW2, cb2, cg2, cbt2, cm2, cv2, ws);

    const int FBLK = NT * 2;   // 1564 embed/gconv blocks (64 nodes each)

    // prologue: CSR fill + embed MLP + stage-0 pool, co-scheduled
    prologue_kernel<<<NFILL + FBLK, 256, 0, stream>>>(
        edges, cursor, col2, ovfCnt, ovf,
        node_ids, emb, ws + WT1_OFF, ws + C1_OFF, ws + WT2_OFF, ws + C2_OFF,
        batch, x0, ws + POOL_OFF, ws + CNT_OFF);

    unsigned* xin = x0;
    unsigned* xout = x1;
    for (int l = 0; l < 3; l++) {
        gconv_fused_kernel<<<FBLK, 256, 0, stream>>>(
            xin, cursor, col2, ovfCnt, ovf,
            ws + WTC1_OFF + l * 4096, ws + CC1_OFF + l * 64,
            ws + WTC2_OFF + l * 4096, ws + CC2_OFF + l * 64,
            batch, xout, ws + POOL_OFF + (long)(l + 1) * GG * 64);
        unsigned* tmp = xin; xin = xout; xout = tmp;
    }

    final_kernel<<<1, 128, 0, stream>>>(
        ws + POOL_OFF, ws + CNT_OFF, linW, linb, (float*)d_out);
}

// Round 17
// 430.542 us; speedup vs baseline: 1.3553x; 1.1159x over previous
//
#include <hip/hip_runtime.h>
#include <hip/hip_bf16.h>

#define NN 100000
#define EE 1000000
#define GG 128
#define NT 782               // node tiles of 128 (782*128 = 100096)
#define BN_EPS 1e-5f
#define SLOTS 48             // fixed CSR row slots; Poisson(10) => P(deg>48) ~ 1e-18

// prologue striping: period 9 = 4 embed + 5 fill, 391 groups
#define PGROUPS 391
#define FBLKN   (PGROUPS * 4)    // 1564 embed blocks (== NT*2)
#define NFILL2  (PGROUPS * 5)    // 1955 fill blocks, 512 edges each

// workspace float offsets
#define X0_OFF    0L          // x ping: packed bf16 [100096][64]
#define X1_OFF    3250000L    // x pong
#define COL2_OFF  6500000L    // slot CSR [100096][48] ints
#define WT1_OFF   12806144L   // fh layer1 scaled cols [128][64]
#define C1_OFF    12814336L
#define WT2_OFF   12814400L   // fh layer2 scaled cols [64][64]
#define C2_OFF    12818496L
#define WTC1_OFF  12818560L   // conv layer1 x3
#define CC1_OFF   12830848L
#define WTC2_OFF  12831040L   // conv layer2 x3
#define CC2_OFF   12843328L
#define POOL_OFF  12843520L   // 4 stages * 128 * 64 (+cnt contiguous)
#define CNT_OFF   12876288L   // 128
#define CUR_OFF   13876416L   // 100,000 ints (degree counters)
#define OVFC_OFF  13976416L   // 1 int (contiguous after cursor)
#define OVF_OFF   13976420L   // overflow pairs (dst,src)

#define OVF_CAP 4096
#define ZERO_INTS (NN + 1 + 4 * GG * 64 + GG)
#define ZBLK ((ZERO_INTS + 255) / 256)           // 520

__device__ __forceinline__ float bf_lo(unsigned v) { return __uint_as_float(v << 16); }
__device__ __forceinline__ float bf_hi(unsigned v) { return __uint_as_float(v & 0xffff0000u); }
__device__ __forceinline__ unsigned f2bf(float f) {
    unsigned b = __float_as_uint(f);
    return (b + 0x7fffu + ((b >> 16) & 1u)) >> 16;   // RNE
}

// ---------------- prep: fold BN into weights + zero cursor/ovf/pooled/cnt ----------------
__global__ void prep_kernel(
    const float* __restrict__ fh_W1, const float* __restrict__ fh_b1, const float* __restrict__ fh_g1,
    const float* __restrict__ fh_bt1, const float* __restrict__ fh_m1, const float* __restrict__ fh_v1,
    const float* __restrict__ fh_W2, const float* __restrict__ fh_b2, const float* __restrict__ fh_g2,
    const float* __restrict__ fh_bt2, const float* __restrict__ fh_m2, const float* __restrict__ fh_v2,
    const float* __restrict__ cW1, const float* __restrict__ cb1, const float* __restrict__ cg1,
    const float* __restrict__ cbt1, const float* __restrict__ cm1, const float* __restrict__ cv1,
    const float* __restrict__ cW2, const float* __restrict__ cb2, const float* __restrict__ cg2,
    const float* __restrict__ cbt2, const float* __restrict__ cm2, const float* __restrict__ cv2,
    float* __restrict__ ws)
{
    int job = blockIdx.x;
    if (job >= 8) {
        long idx = (long)(job - 8) * 256 + threadIdx.x;
        if (idx < NN + 1) {
            ((int*)(ws + CUR_OFF))[idx] = 0;            // cursor + ovfCnt
        } else {
            long i2 = idx - (NN + 1);
            if (i2 < 4L * GG * 64 + GG) (ws + POOL_OFF)[i2] = 0.f;   // pooled + cnt
        }
        return;
    }
    const float *W, *b, *g, *bt, *m, *v;
    float *Wo, *Co;
    int K;
    if (job == 0) {
        W = fh_W1; b = fh_b1; g = fh_g1; bt = fh_bt1; m = fh_m1; v = fh_v1;
        Wo = ws + WT1_OFF; Co = ws + C1_OFF; K = 128;
    } else if (job == 1) {
        W = fh_W2; b = fh_b2; g = fh_g2; bt = fh_bt2; m = fh_m2; v = fh_v2;
        Wo = ws + WT2_OFF; Co = ws + C2_OFF; K = 64;
    } else if (job <= 4) {
        int l = job - 2;
        W = cW1 + l * 4096; b = cb1 + l * 64; g = cg1 + l * 64; bt = cbt1 + l * 64;
        m = cm1 + l * 64; v = cv1 + l * 64;
        Wo = ws + WTC1_OFF + l * 4096; Co = ws + CC1_OFF + l * 64; K = 64;
    } else {
        int l = job - 5;
        W = cW2 + l * 4096; b = cb2 + l * 64; g = cg2 + l * 64; bt = cbt2 + l * 64;
        m = cm2 + l * 64; v = cv2 + l * 64;
        Wo = ws + WTC2_OFF + l * 4096; Co = ws + CC2_OFF + l * 64; K = 64;
    }
    int tot = 64 * K;
    for (int i = threadIdx.x; i < tot; i += blockDim.x) {
        int j = i & 63;
        float s = g[j] * rsqrtf(v[j] + BN_EPS);
        Wo[i] = W[i] * s;   // [k][j] layout, scale column j
    }
    if (threadIdx.x < 64) {
        int j = threadIdx.x;
        float s = g[j] * rsqrtf(v[j] + BN_EPS);
        Co[j] = (b[j] - m[j]) * s + bt[j];
    }
}

// ---------------- prologue: STRIPED slot-CSR fill + embed MLP ----------------
// Period-9 block striping (4 embed + 5 fill) so every CU holds a mix of
// latency-bound fill waves and VALU-bound embed waves throughout.
__global__ __launch_bounds__(256) void prologue_kernel(
    const int* __restrict__ edges, int* __restrict__ cursor, int* __restrict__ col2,
    int* __restrict__ ovfCnt, int* __restrict__ ovf,
    const int* __restrict__ node_ids, const float* __restrict__ emb,
    const float* __restrict__ W1s, const float* __restrict__ C1v,
    const float* __restrict__ W2s, const float* __restrict__ C2v,
    const int* __restrict__ batch,
    unsigned* __restrict__ xb, float* __restrict__ pooled, float* __restrict__ cnt)
{
    __shared__ float ldsB[64 * 65];   // E half [node][k] -> later H [feat][node]
    __shared__ int sh_nid[64];
    int t = threadIdx.x;
    int r = blockIdx.x % 9, grp = blockIdx.x / 9;

    if (r >= 4) {
        // ---- fill path: 512 edges per block, 2 per thread ----
        long f = (long)grp * 5 + (r - 4);
        long e0 = f * 512 + t;
        long e1 = e0 + 256;
        if (e0 < EE) {
            int dst = edges[EE + e0];
            int src = edges[e0];
            int p = atomicAdd(&cursor[dst], 1);
            if (p < SLOTS) {
                col2[(long)dst * SLOTS + p] = src;
            } else {
                int q = atomicAdd(ovfCnt, 1);
                if (q < OVF_CAP) { ovf[2 * q] = dst; ovf[2 * q + 1] = src; }
            }
        }
        if (e1 < EE) {
            int dst = edges[EE + e1];
            int src = edges[e1];
            int p = atomicAdd(&cursor[dst], 1);
            if (p < SLOTS) {
                col2[(long)dst * SLOTS + p] = src;
            } else {
                int q = atomicAdd(ovfCnt, 1);
                if (q < OVF_CAP) { ovf[2 * q] = dst; ovf[2 * q + 1] = src; }
            }
        }
        return;
    }

    // ---- embed path ----
    int eb = grp * 4 + r;            // 0..1563
    int lane = t & 63;
    int wvu = __builtin_amdgcn_readfirstlane(t >> 6);
    int nbase = eb << 6;
    if (t < 64) {
        int n0 = nbase + t;
        sh_nid[t] = (n0 < NN) ? node_ids[n0] : 0;
    }
    __syncthreads();

    float a[16];
#pragma unroll
    for (int j = 0; j < 16; j++) a[j] = C1v[wvu * 16 + j];

#pragma unroll
    for (int half = 0; half < 2; half++) {
        for (int idx = t; idx < 4096; idx += 256) {
            int rr = idx >> 6, c = idx & 63;
            ldsB[rr * 65 + c] = emb[(long)sh_nid[rr] * 128 + half * 64 + c];
        }
        __syncthreads();
#pragma unroll 4
        for (int k = 0; k < 64; k++) {
            float ek = ldsB[lane * 65 + k];
            const float* w = W1s + (half * 64 + k) * 64 + wvu * 16;
#pragma unroll
            for (int j = 0; j < 16; j++) a[j] += ek * w[j];
        }
        __syncthreads();
    }

#pragma unroll
    for (int j = 0; j < 16; j++) ldsB[(wvu * 16 + j) * 65 + lane] = fmaxf(a[j], 0.f);
    __syncthreads();
    float o[16];
#pragma unroll
    for (int j = 0; j < 16; j++) o[j] = C2v[wvu * 16 + j];
#pragma unroll 4
    for (int k = 0; k < 64; k++) {
        float hk = ldsB[k * 65 + lane];
        const float* w = W2s + k * 64 + wvu * 16;
#pragma unroll
        for (int j = 0; j < 16; j++) o[j] += hk * w[j];
    }
#pragma unroll
    for (int j = 0; j < 16; j++) o[j] = fmaxf(o[j], 0.f);

    int n = nbase + lane;
    if (n < NN) {
        unsigned u[8];
#pragma unroll
        for (int p = 0; p < 8; p++) u[p] = f2bf(o[2 * p]) | (f2bf(o[2 * p + 1]) << 16);
        uint4* xo = (uint4*)(xb + ((long)n << 5) + (wvu << 3));
        xo[0] = make_uint4(u[0], u[1], u[2], u[3]);
        xo[1] = make_uint4(u[4], u[5], u[6], u[7]);
    }

    int bg = (n < NN) ? batch[n] : -1;
    int bprev = __shfl(bg, (lane == 0) ? 0 : lane - 1);
    bool bound = (lane == 0) || (bg != bprev);
    unsigned long long m = __ballot(bound);
    int p = 0;
    while (p < 64) {
        unsigned long long rest = (p < 63) ? (m & (~0ULL << (p + 1))) : 0ULL;
        int np = rest ? (__ffsll((long long)rest) - 1) : 64;
        int g = __shfl(bg, p);
        if (g >= 0) {
            bool in = (lane >= p) && (lane < np);
#pragma unroll
            for (int j = 0; j < 16; j++) {
                float v = in ? o[j] : 0.f;
                v += __shfl_xor(v, 1);  v += __shfl_xor(v, 2);
                v += __shfl_xor(v, 4);  v += __shfl_xor(v, 8);
                v += __shfl_xor(v, 16); v += __shfl_xor(v, 32);
                if (lane == p) unsafeAtomicAdd(&pooled[g * 64 + wvu * 16 + j], v);
            }
            if (wvu == 0 && lane == p) unsafeAtomicAdd(&cnt[g], (float)(np - p));
        }
        p = np;
    }
}

// ---------------- fused gather + conv MLP + pool (slot CSR, single LDS buffer) ----------------
__global__ __launch_bounds__(256) void gconv_fused_kernel(
    const unsigned* __restrict__ xin, const int* __restrict__ cursor, const int* __restrict__ col2,
    const int* __restrict__ ovfCnt, const int* __restrict__ ovf,
    const float* __restrict__ W1s, const float* __restrict__ C1v,
    const float* __restrict__ W2s, const float* __restrict__ C2v,
    const int* __restrict__ batch,
    unsigned* __restrict__ xout, float* __restrict__ pooled)
{
    __shared__ float ldsB[64 * 65];   // gather acc [feat][node] -> later H
    __shared__ int sh_no;
    int t = threadIdx.x;
    int lane = t & 63;
    int wv = t >> 6;
    int nbase = blockIdx.x << 6;
    if (t == 0) sh_no = *ovfCnt;

    int nL = nbase + lane;
    int myDeg = 0;
    if (nL < NN) {
        myDeg = cursor[nL];
        if (myDeg > SLOTS) myDeg = SLOTS;
    }

    {
        int q = lane >> 3, c = lane & 7;
        const uint4* x4 = (const uint4*)xin;
        for (int s = 0; s < 16; s++) {
            int i = (wv << 4) + s;
            int n = nbase + i;
            if (n < NN) {
                int deg = __shfl(myDeg, i);
                long cb = (long)n * SLOTS;
                float acc[8];
                if (q == 0) {
                    uint4 u = x4[(long)n * 8 + c];
                    acc[0] = bf_lo(u.x); acc[1] = bf_hi(u.x);
                    acc[2] = bf_lo(u.y); acc[3] = bf_hi(u.y);
                    acc[4] = bf_lo(u.z); acc[5] = bf_hi(u.z);
                    acc[6] = bf_lo(u.w); acc[7] = bf_hi(u.w);
                } else {
#pragma unroll
                    for (int r = 0; r < 8; r++) acc[r] = 0.f;
                }
                for (int b2 = q; b2 < deg; b2 += 8) {
                    int sc = col2[cb + b2];
                    uint4 u = x4[(long)sc * 8 + c];
                    acc[0] += bf_lo(u.x); acc[1] += bf_hi(u.x);
                    acc[2] += bf_lo(u.y); acc[3] += bf_hi(u.y);
                    acc[4] += bf_lo(u.z); acc[5] += bf_hi(u.z);
                    acc[6] += bf_lo(u.w); acc[7] += bf_hi(u.w);
                }
#pragma unroll
                for (int d = 8; d <= 32; d <<= 1) {
#pragma unroll
                    for (int r = 0; r < 8; r++) acc[r] += __shfl_xor(acc[r], d);
                }
                if (q == 0) {
                    int f = c << 3;
#pragma unroll
                    for (int r = 0; r < 8; r++) ldsB[(f + r) * 65 + i] = acc[r];
                }
            }
        }
    }
    __syncthreads();

    if (sh_no > 0) {
        if (t == 0) {
            int no = sh_no; if (no > OVF_CAP) no = OVF_CAP;
            for (int i = 0; i < no; i++) {
                int dst = ovf[2 * i];
                if (dst >= nbase && dst < nbase + 64 && dst < NN) {
                    int src = ovf[2 * i + 1];
                    int loc = dst - nbase;
                    const unsigned* xr = xin + ((long)src << 5);
                    for (int f = 0; f < 32; f++) {
                        unsigned v = xr[f];
                        ldsB[(2 * f) * 65 + loc] += bf_lo(v);
                        ldsB[(2 * f + 1) * 65 + loc] += bf_hi(v);
                    }
                }
            }
        }
        __syncthreads();
    }

    int wvu = __builtin_amdgcn_readfirstlane(wv);
    float a[16];
#pragma unroll
    for (int j = 0; j < 16; j++) a[j] = C1v[wvu * 16 + j];
#pragma unroll 4
    for (int k = 0; k < 64; k++) {
        float xk = ldsB[k * 65 + lane];
        const float* w = W1s + k * 64 + wvu * 16;
#pragma unroll
        for (int j = 0; j < 16; j++) a[j] += xk * w[j];
    }
    __syncthreads();
#pragma unroll
    for (int j = 0; j < 16; j++) ldsB[(wvu * 16 + j) * 65 + lane] = fmaxf(a[j], 0.f);
    __syncthreads();

    float o[16];
#pragma unroll
    for (int j = 0; j < 16; j++) o[j] = C2v[wvu * 16 + j];
#pragma unroll 4
    for (int k = 0; k < 64; k++) {
        float hk = ldsB[k * 65 + lane];
        const float* w = W2s + k * 64 + wvu * 16;
#pragma unroll
        for (int j = 0; j < 16; j++) o[j] += hk * w[j];
    }
#pragma unroll
    for (int j = 0; j < 16; j++) o[j] = fmaxf(o[j], 0.f);

    int n = nbase + lane;
    if (xout != nullptr && n < NN) {     // last layer: x is dead, skip write
        unsigned u[8];
#pragma unroll
        for (int p = 0; p < 8; p++) u[p] = f2bf(o[2 * p]) | (f2bf(o[2 * p + 1]) << 16);
        uint4* xo = (uint4*)(xout + ((long)n << 5) + (wvu << 3));
        xo[0] = make_uint4(u[0], u[1], u[2], u[3]);
        xo[1] = make_uint4(u[4], u[5], u[6], u[7]);
    }

    int bg = (n < NN) ? batch[n] : -1;
    int bprev = __shfl(bg, (lane == 0) ? 0 : lane - 1);
    bool bound = (lane == 0) || (bg != bprev);
    unsigned long long m = __ballot(bound);
    int p = 0;
    while (p < 64) {
        unsigned long long rest = (p < 63) ? (m & (~0ULL << (p + 1))) : 0ULL;
        int np = rest ? (__ffsll((long long)rest) - 1) : 64;
        int g = __shfl(bg, p);
        if (g >= 0) {
            bool in = (lane >= p) && (lane < np);
#pragma unroll
            for (int j = 0; j < 16; j++) {
                float v = in ? o[j] : 0.f;
                v += __shfl_xor(v, 1);  v += __shfl_xor(v, 2);
                v += __shfl_xor(v, 4);  v += __shfl_xor(v, 8);
                v += __shfl_xor(v, 16); v += __shfl_xor(v, 32);
                if (lane == p) unsafeAtomicAdd(&pooled[g * 64 + wvu * 16 + j], v);
            }
        }
        p = np;
    }
}

// ---------------- readout + softmax ----------------
__global__ void final_kernel(
    const float* __restrict__ pooled, const float* __restrict__ cnt,
    const float* __restrict__ linW, const float* __restrict__ linb,
    float* __restrict__ outp)
{
    int g = threadIdx.x;
    if (g >= GG) return;
    float z0 = 0.f, z1 = 0.f;
    float c = cnt[g];
    for (int l = 0; l < 4; l++) {
        const float* p = pooled + (long)l * GG * 64 + (long)g * 64;
        const float* W = linW + l * 128;
        float bscale = (l == 0) ? c : 1.f;
        float s0 = linb[l * 2 + 0] * bscale;
        float s1 = linb[l * 2 + 1] * bscale;
        for (int k = 0; k < 64; k++) {
            float pk = p[k];
            s0 += pk * W[k * 2 + 0];
            s1 += pk * W[k * 2 + 1];
        }
        z0 += s0; z1 += s1;
    }
    float mx = fmaxf(z0, z1);
    float e0 = expf(z0 - mx), e1 = expf(z1 - mx);
    float inv = 1.f / (e0 + e1);
    outp[g * 2 + 0] = e0 * inv;
    outp[g * 2 + 1] = e1 * inv;
}

extern "C" void kernel_launch(void* const* d_in, const int* in_sizes, int n_in,
                              void* d_out, int out_size, void* d_ws, size_t ws_size,
                              hipStream_t stream) {
    const int*   node_ids = (const int*)d_in[0];
    const int*   edges    = (const int*)d_in[1];
    const int*   batch    = (const int*)d_in[2];
    const float* emb      = (const float*)d_in[3];
    const float* fh_W1 = (const float*)d_in[4];
    const float* fh_b1 = (const float*)d_in[5];
    const float* fh_g1 = (const float*)d_in[6];
    const float* fh_bt1 = (const float*)d_in[7];
    const float* fh_m1 = (const float*)d_in[8];
    const float* fh_v1 = (const float*)d_in[9];
    const float* fh_W2 = (const float*)d_in[10];
    const float* fh_b2 = (const float*)d_in[11];
    const float* fh_g2 = (const float*)d_in[12];
    const float* fh_bt2 = (const float*)d_in[13];
    const float* fh_m2 = (const float*)d_in[14];
    const float* fh_v2 = (const float*)d_in[15];
    const float* cW1 = (const float*)d_in[16];
    const float* cb1 = (const float*)d_in[17];
    const float* cg1 = (const float*)d_in[18];
    const float* cbt1 = (const float*)d_in[19];
    const float* cm1 = (const float*)d_in[20];
    const float* cv1 = (const float*)d_in[21];
    const float* cW2 = (const float*)d_in[22];
    const float* cb2 = (const float*)d_in[23];
    const float* cg2 = (const float*)d_in[24];
    const float* cbt2 = (const float*)d_in[25];
    const float* cm2 = (const float*)d_in[26];
    const float* cv2 = (const float*)d_in[27];
    const float* linW = (const float*)d_in[28];
    const float* linb = (const float*)d_in[29];

    float*    ws     = (float*)d_ws;
    int*      cursor = (int*)(ws + CUR_OFF);
    int*      col2   = (int*)(ws + COL2_OFF);
    int*      ovfCnt = (int*)(ws + OVFC_OFF);
    int*      ovf    = (int*)(ws + OVF_OFF);
    unsigned* x0     = (unsigned*)(ws + X0_OFF);
    unsigned* x1     = (unsigned*)(ws + X1_OFF);

    prep_kernel<<<8 + ZBLK, 256, 0, stream>>>(
        fh_W1, fh_b1, fh_g1, fh_bt1, fh_m1, fh_v1,
        fh_W2, fh_b2, fh_g2, fh_bt2, fh_m2, fh_v2,
        cW1, cb1, cg1, cbt1, cm1, cv1,
        cW2, cb2, cg2, cbt2, cm2, cv2, ws);

    const int FBLK = NT * 2;   // 1564 gconv blocks (64 nodes each)

    // prologue: striped CSR fill + embed MLP + stage-0 pool
    prologue_kernel<<<PGROUPS * 9, 256, 0, stream>>>(
        edges, cursor, col2, ovfCnt, ovf,
        node_ids, emb, ws + WT1_OFF, ws + C1_OFF, ws + WT2_OFF, ws + C2_OFF,
        batch, x0, ws + POOL_OFF, ws + CNT_OFF);

    unsigned* xin = x0;
    unsigned* xout = x1;
    for (int l = 0; l < 3; l++) {
        gconv_fused_kernel<<<FBLK, 256, 0, stream>>>(
            xin, cursor, col2, ovfCnt, ovf,
            ws + WTC1_OFF + l * 4096, ws + CC1_OFF + l * 64,
            ws + WTC2_OFF + l * 4096, ws + CC2_OFF + l * 64,
            batch, (l == 2) ? nullptr : xout,
            ws + POOL_OFF + (long)(l + 1) * GG * 64);
        unsigned* tmp = xin; xin = xout; xout = tmp;
    }

    final_kernel<<<1, 128, 0, stream>>>(
        ws + POOL_OFF, ws + CNT_OFF, linW, linb, (float*)d_out);
}